// Round 1
// baseline (6027.638 us; speedup 1.0000x reference)
//
#include <hip/hip_runtime.h>
#include <cstdint>
#include <cstddef>

// Problem constants: B=16, E=16, T=1024, F=80, H=8, 3H=24 qkv channels
#define NB 16
#define NT 1024
#define NF 80
#define NH 8

static const size_t QKV_ELEMS = (size_t)NB * 24 * NT * NF;  // 31,457,280
static const size_t OUT_ELEMS = (size_t)NB * 16 * NT * NF;  // 20,971,520
static const size_t AW_ELEMS  = (size_t)NB * NT * NT;       // 16,777,216

// ---------------------------------------------------------------------------
// conv3x3 SAME, NCHW input (16 in-channels), OIHW weights. QSCALE multiplies
// output channels 0..7 by 0.25 (the q scaling folded into the conv).
// block: (t-tile of 8 rows) x (batch). 256 threads.
// ---------------------------------------------------------------------------
template <int OC, bool QSCALE>
__global__ __launch_bounds__(256) void conv3x3_k(
    const float* __restrict__ x, const float* __restrict__ w,
    const float* __restrict__ bias, float* __restrict__ out) {
  __shared__ float xt[16][10][84];   // [c][t-halo][f-halo(82, padded 84)]
  __shared__ float wt[OC * 16 * 9];
  __shared__ float bt[OC];
  const int b = blockIdx.y, t0 = blockIdx.x * 8;
  const int tid = threadIdx.x;
  for (int i = tid; i < OC * 144; i += 256) wt[i] = w[i];
  if (tid < OC) bt[tid] = bias[tid];
  for (int i = tid; i < 16 * 10 * 82; i += 256) {
    int c = i / 820, r = (i % 820) / 82, j = i % 82;
    int t = t0 + r - 1, f = j - 1;
    float v = 0.f;
    if (t >= 0 && t < NT && f >= 0 && f < NF)
      v = x[((size_t)(b * 16 + c) * NT + t) * NF + f];
    xt[c][r][j] = v;
  }
  __syncthreads();
  const int NTASK = OC * 8 * 20;  // each task = 4 consecutive f outputs
  for (int task = tid; task < NTASK; task += 256) {
    int oc = task / 160;
    int rem = task % 160;
    int tt = rem / 20;
    int fb = (rem % 20) * 4;
    float a0 = bt[oc], a1 = a0, a2 = a0, a3 = a0;
    for (int c = 0; c < 16; ++c) {
#pragma unroll
      for (int kt = 0; kt < 3; ++kt) {
        const float* wp = &wt[((oc * 16 + c) * 3 + kt) * 3];
        float w0 = wp[0], w1 = wp[1], w2 = wp[2];
        const float* xr = &xt[c][tt + kt][fb];
        float x0 = xr[0], x1 = xr[1], x2 = xr[2], x3 = xr[3], x4 = xr[4],
              x5 = xr[5];
        a0 += w0 * x0 + w1 * x1 + w2 * x2;
        a1 += w0 * x1 + w1 * x2 + w2 * x3;
        a2 += w0 * x2 + w1 * x3 + w2 * x4;
        a3 += w0 * x3 + w1 * x4 + w2 * x5;
      }
    }
    if (QSCALE && oc < 8) { a0 *= 0.25f; a1 *= 0.25f; a2 *= 0.25f; a3 *= 0.25f; }
    float* op = out + ((size_t)(b * OC + oc) * NT + t0 + tt) * NF + fb;
    op[0] = a0; op[1] = a1; op[2] = a2; op[3] = a3;
  }
}

// ---------------------------------------------------------------------------
// BatchNorm stats: per (batch, channel) block computes partial sum / sumsq.
// grid (16, C). Deterministic (fixed-order tree reduction, no atomics).
// ---------------------------------------------------------------------------
__global__ __launch_bounds__(256) void bn_stats_k(const float* __restrict__ x,
                                                  float* __restrict__ partials,
                                                  int C) {
  const int b = blockIdx.x, c = blockIdx.y;
  const float4* p = (const float4*)(x + (size_t)(b * C + c) * (NT * NF));
  float s = 0.f, s2 = 0.f;
  for (int i = threadIdx.x; i < (NT * NF) / 4; i += 256) {
    float4 v = p[i];
    s += v.x + v.y + v.z + v.w;
    s2 += v.x * v.x + v.y * v.y + v.z * v.z + v.w * v.w;
  }
  __shared__ float rs[256], rs2[256];
  rs[threadIdx.x] = s;
  rs2[threadIdx.x] = s2;
  __syncthreads();
  for (int off = 128; off > 0; off >>= 1) {
    if ((int)threadIdx.x < off) {
      rs[threadIdx.x] += rs[threadIdx.x + off];
      rs2[threadIdx.x] += rs2[threadIdx.x + off];
    }
    __syncthreads();
  }
  if (threadIdx.x == 0) {
    partials[(c * 16 + b) * 2 + 0] = rs[0];
    partials[(c * 16 + b) * 2 + 1] = rs2[0];
  }
}

__global__ void bn_finalize_k(const float* __restrict__ partials,
                              float* __restrict__ stats, int C) {
  int c = threadIdx.x;
  if (c < C) {
    float s = 0.f, s2 = 0.f;
    for (int i = 0; i < 16; ++i) {
      s += partials[(c * 16 + i) * 2 + 0];
      s2 += partials[(c * 16 + i) * 2 + 1];
    }
    const float N = 16.0f * (float)(NT * NF);
    float mean = s / N;
    float var = s2 / N - mean * mean;
    stats[c * 2 + 0] = mean;
    stats[c * 2 + 1] = rsqrtf(var + 1e-5f);
  }
}

// normalize + relu in place on qkv (24 channels; q uses gq/bq, k gk/bk, v gv/bv)
__global__ __launch_bounds__(256) void bn_apply_qkv_k(
    float* __restrict__ qkv, const float* __restrict__ stats,
    const float* __restrict__ gq, const float* __restrict__ bq,
    const float* __restrict__ gk, const float* __restrict__ bk,
    const float* __restrict__ gv, const float* __restrict__ bv) {
  const size_t n4 = QKV_ELEMS / 4;
  const size_t stride = (size_t)gridDim.x * blockDim.x;
  for (size_t idx = (size_t)blockIdx.x * blockDim.x + threadIdx.x; idx < n4;
       idx += stride) {
    int c = (int)((idx / (NT * NF / 4)) % 24);
    float g, be;
    if (c < 8) { g = gq[c]; be = bq[c]; }
    else if (c < 16) { g = gk[c - 8]; be = bk[c - 8]; }
    else { g = gv[c - 16]; be = bv[c - 16]; }
    float mean = stats[c * 2 + 0], invstd = stats[c * 2 + 1];
    float4 v = ((float4*)qkv)[idx];
    v.x = fmaxf((v.x - mean) * invstd * g + be, 0.f);
    v.y = fmaxf((v.y - mean) * invstd * g + be, 0.f);
    v.z = fmaxf((v.z - mean) * invstd * g + be, 0.f);
    v.w = fmaxf((v.w - mean) * invstd * g + be, 0.f);
    ((float4*)qkv)[idx] = v;
  }
}

// normalize + relu: read y (ws), write final out region of d_out (16 channels)
__global__ __launch_bounds__(256) void bn_apply_out_k(
    const float* __restrict__ y, const float* __restrict__ stats,
    const float* __restrict__ go, const float* __restrict__ bo,
    float* __restrict__ out) {
  const size_t n4 = OUT_ELEMS / 4;
  const size_t stride = (size_t)gridDim.x * blockDim.x;
  for (size_t idx = (size_t)blockIdx.x * blockDim.x + threadIdx.x; idx < n4;
       idx += stride) {
    int c = (int)((idx / (NT * NF / 4)) % 16);
    float g = go[c], be = bo[c];
    float mean = stats[c * 2 + 0], invstd = stats[c * 2 + 1];
    float4 v = ((const float4*)y)[idx];
    v.x = fmaxf((v.x - mean) * invstd * g + be, 0.f);
    v.y = fmaxf((v.y - mean) * invstd * g + be, 0.f);
    v.z = fmaxf((v.z - mean) * invstd * g + be, 0.f);
    v.w = fmaxf((v.w - mean) * invstd * g + be, 0.f);
    ((float4*)out)[idx] = v;
  }
}

// ---------------------------------------------------------------------------
// Time attention. Block = (t-tile of 16 rows, batch), loops h=0..7 inside so
// aw_t_avg accumulates in registers (no atomics). Full 16x1024 S tile in LDS.
// attn_t -> out channels 0..7. aw_avg = sum_h P / 8.
// ---------------------------------------------------------------------------
__global__ __launch_bounds__(256) void time_attn_k(
    const float* __restrict__ qkv, float* __restrict__ attn_out,
    float* __restrict__ aw_avg) {
  __shared__ float s_lds[16][1024];  // 64 KB
  __shared__ float q_lds[16][81];
  __shared__ float kv_lds[32][81];
  const int b = blockIdx.y, t0 = blockIdx.x * 16;
  const int tid = threadIdx.x;
  const int grp = tid >> 4, lane = tid & 15;  // 16 groups x 16 lanes
  float avg_acc[64];
#pragma unroll
  for (int k = 0; k < 64; ++k) avg_acc[k] = 0.f;

  for (int h = 0; h < NH; ++h) {
    const float* qb = qkv + (size_t)(b * 24 + h) * NT * NF;
    const float* kb = qkv + (size_t)(b * 24 + 8 + h) * NT * NF;
    const float* vb = qkv + (size_t)(b * 24 + 16 + h) * NT * NF;
    // load Q tile
    for (int idx = tid; idx < 16 * NF; idx += 256)
      q_lds[idx / NF][idx % NF] = qb[(size_t)(t0 + idx / NF) * NF + idx % NF];
    __syncthreads();
    // S = Q K^T : 32 s-tiles of 32 rows
    const int jj = tid & 31, tl = tid >> 5;  // tl 0..7 -> rows tl, tl+8
    for (int st = 0; st < 32; ++st) {
      int s0 = st * 32;
      for (int idx = tid; idx < 32 * NF; idx += 256)
        kv_lds[idx / NF][idx % NF] =
            kb[(size_t)(s0 + idx / NF) * NF + idx % NF];
      __syncthreads();
      float a0 = 0.f, a1 = 0.f;
      for (int f = 0; f < NF; ++f) {
        float kvv = kv_lds[jj][f];
        a0 += q_lds[tl][f] * kvv;
        a1 += q_lds[tl + 8][f] * kvv;
      }
      s_lds[tl][s0 + jj] = a0;
      s_lds[tl + 8][s0 + jj] = a1;
      __syncthreads();
    }
    // softmax: row grp handled by its 16-lane group
    float m = -1e30f;
    for (int j = lane; j < NT; j += 16) m = fmaxf(m, s_lds[grp][j]);
#pragma unroll
    for (int mk = 8; mk; mk >>= 1) m = fmaxf(m, __shfl_xor(m, mk, 16));
    float dsum = 0.f;
    for (int j = lane; j < NT; j += 16) {
      float e = expf(s_lds[grp][j] - m);
      dsum += e;
      s_lds[grp][j] = e;
    }
#pragma unroll
    for (int mk = 8; mk; mk >>= 1) dsum += __shfl_xor(dsum, mk, 16);
    float invd = 1.f / dsum;
    for (int j = lane; j < NT; j += 16) s_lds[grp][j] *= invd;
    // accumulate head-average (reads only own-lane-written entries)
#pragma unroll
    for (int k = 0; k < 64; ++k) avg_acc[k] += s_lds[grp][lane + 16 * k];
    __syncthreads();  // all P finalized before cross-lane PV reads
    // O = P V
    float o[5] = {0.f, 0.f, 0.f, 0.f, 0.f};
    for (int vt = 0; vt < 32; ++vt) {
      int s0 = vt * 32;
      for (int idx = tid; idx < 32 * NF; idx += 256)
        kv_lds[idx / NF][idx % NF] =
            vb[(size_t)(s0 + idx / NF) * NF + idx % NF];
      __syncthreads();
#pragma unroll 8
      for (int j = 0; j < 32; ++j) {
        float p = s_lds[grp][s0 + j];
#pragma unroll
        for (int i = 0; i < 5; ++i) o[i] += p * kv_lds[j][lane + 16 * i];
      }
      __syncthreads();
    }
    float* ob = attn_out + ((size_t)(b * 16 + h) * NT + t0 + grp) * NF;
#pragma unroll
    for (int i = 0; i < 5; ++i) ob[lane + 16 * i] = o[i];
  }
  float* ab = aw_avg + ((size_t)b * NT + t0 + grp) * NT;
#pragma unroll
  for (int k = 0; k < 64; ++k) ab[lane + 16 * k] = avg_acc[k] * 0.125f;
}

// ---------------------------------------------------------------------------
// Freq attention. Block per (b,h). C[f,g] = sum_t q[t,f] k[t,g]; softmax rows;
// attn2[t,f] = sum_g P[f,g] v[t,g]  -> out channels 8..15.
// ---------------------------------------------------------------------------
__global__ __launch_bounds__(256) void freq_attn_k(const float* __restrict__ qkv,
                                                   float* __restrict__ attn_out) {
  __shared__ float a_lds[64][81];  // q tile / v tile
  __shared__ float b_lds[64][81];  // k tile
  __shared__ float c_lds[80][81];  // scores / probs
  const int bh = blockIdx.x;
  const int b = bh >> 3, h = bh & 7;
  const float* qb = qkv + (size_t)(b * 24 + h) * NT * NF;
  const float* kb = qkv + (size_t)(b * 24 + 8 + h) * NT * NF;
  const float* vb = qkv + (size_t)(b * 24 + 16 + h) * NT * NF;
  const int tid = threadIdx.x;
  const int f0 = (tid & 15) * 5, g0 = (tid >> 4) * 5;
  float acc[5][5];
#pragma unroll
  for (int i = 0; i < 5; ++i)
#pragma unroll
    for (int j = 0; j < 5; ++j) acc[i][j] = 0.f;

  for (int tt = 0; tt < 16; ++tt) {
    int t0 = tt * 64;
    for (int idx = tid; idx < 64 * NF; idx += 256) {
      int r = idx / NF, f = idx % NF;
      a_lds[r][f] = qb[(size_t)(t0 + r) * NF + f];
      b_lds[r][f] = kb[(size_t)(t0 + r) * NF + f];
    }
    __syncthreads();
    for (int r = 0; r < 64; ++r) {
      float qv[5], kv[5];
#pragma unroll
      for (int i = 0; i < 5; ++i) {
        qv[i] = a_lds[r][f0 + i];
        kv[i] = b_lds[r][g0 + i];
      }
#pragma unroll
      for (int i = 0; i < 5; ++i)
#pragma unroll
        for (int j = 0; j < 5; ++j) acc[i][j] += qv[i] * kv[j];
    }
    __syncthreads();
  }
#pragma unroll
  for (int i = 0; i < 5; ++i)
#pragma unroll
    for (int j = 0; j < 5; ++j) c_lds[f0 + i][g0 + j] = acc[i][j];
  __syncthreads();
  if (tid < 80) {
    float m = -1e30f;
    for (int g = 0; g < 80; ++g) m = fmaxf(m, c_lds[tid][g]);
    float dsum = 0.f;
    for (int g = 0; g < 80; ++g) {
      float e = expf(c_lds[tid][g] - m);
      dsum += e;
      c_lds[tid][g] = e;
    }
    float invd = 1.f / dsum;
    for (int g = 0; g < 80; ++g) c_lds[tid][g] *= invd;
  }
  __syncthreads();
  float* ob = attn_out + (size_t)(b * 16 + 8 + h) * NT * NF;
  for (int vt = 0; vt < 16; ++vt) {
    int t0 = vt * 64;
    for (int idx = tid; idx < 64 * NF; idx += 256)
      a_lds[idx / NF][idx % NF] = vb[(size_t)(t0 + idx / NF) * NF + idx % NF];
    __syncthreads();
    const int t = tid & 63;
    const int fg = tid >> 6;  // 4 groups of 20 f
    float oacc[20];
#pragma unroll
    for (int i = 0; i < 20; ++i) oacc[i] = 0.f;
    for (int g = 0; g < 80; ++g) {
      float vv = a_lds[t][g];
#pragma unroll
      for (int i = 0; i < 20; ++i) oacc[i] += vv * c_lds[fg * 20 + i][g];
    }
    float4* ob4 = (float4*)(ob + (size_t)(t0 + t) * NF + fg * 20);
#pragma unroll
    for (int m4 = 0; m4 < 5; ++m4)
      ob4[m4] = make_float4(oacc[4 * m4], oacc[4 * m4 + 1], oacc[4 * m4 + 2],
                            oacc[4 * m4 + 3]);
    __syncthreads();
  }
}

// ---------------------------------------------------------------------------
extern "C" void kernel_launch(void* const* d_in, const int* in_sizes, int n_in,
                              void* d_out, int out_size, void* d_ws,
                              size_t ws_size, hipStream_t stream) {
  const float* x = (const float*)d_in[0];
  const float* w_in = (const float*)d_in[1];
  const float* b_in = (const float*)d_in[2];
  const float* w_out = (const float*)d_in[3];
  const float* b_out = (const float*)d_in[4];
  const float* gq = (const float*)d_in[5];
  const float* bq = (const float*)d_in[6];
  const float* gk = (const float*)d_in[7];
  const float* bk = (const float*)d_in[8];
  const float* gv = (const float*)d_in[9];
  const float* bv = (const float*)d_in[10];
  const float* go = (const float*)d_in[11];
  const float* bo = (const float*)d_in[12];

  float* out = (float*)d_out;            // (16,16,1024,80)
  float* aw = out + OUT_ELEMS;           // (16,1024,1024)
  float* ws = (float*)d_ws;
  float* qkv = ws;                       // 31,457,280 floats; later aliased by y
  float* partials = ws + QKV_ELEMS;      // up to 768 floats
  float* stats1 = partials + 768;        // 48
  float* stats2 = stats1 + 48;           // 32

  // conv_in (+ folded q scaling) -> qkv
  conv3x3_k<24, true><<<dim3(128, 16), 256, 0, stream>>>(x, w_in, b_in, qkv);
  // BN stats + normalize + relu (in place)
  bn_stats_k<<<dim3(16, 24), 256, 0, stream>>>(qkv, partials, 24);
  bn_finalize_k<<<1, 64, 0, stream>>>(partials, stats1, 24);
  bn_apply_qkv_k<<<4096, 256, 0, stream>>>(qkv, stats1, gq, bq, gk, bk, gv, bv);
  // attention; attn tensor staged in the `out` region of d_out
  time_attn_k<<<dim3(64, 16), 256, 0, stream>>>(qkv, out, aw);
  freq_attn_k<<<128, 256, 0, stream>>>(qkv, out);
  // conv_out reads attn (d_out), writes y into ws (aliases qkv, now dead)
  conv3x3_k<16, false><<<dim3(128, 16), 256, 0, stream>>>(out, w_out, b_out,
                                                          qkv);
  // final BN + relu -> out
  bn_stats_k<<<dim3(16, 16), 256, 0, stream>>>(qkv, partials, 16);
  bn_finalize_k<<<1, 64, 0, stream>>>(partials, stats2, 16);
  bn_apply_out_k<<<4096, 256, 0, stream>>>(qkv, stats2, go, bo, out);
}

// Round 4
// 2163.987 us; speedup vs baseline: 2.7854x; 2.7854x over previous
//
#include <hip/hip_runtime.h>
#include <hip/hip_bf16.h>
#include <cstdint>
#include <cstddef>

// Problem constants: B=16, E=16, T=1024, F=80, H=8, 3H=24 qkv channels
#define NB 16
#define NT 1024
#define NF 80
#define NH 8
#define FP 96   // f padded to 96 (3 x K=32 MFMA steps); pad is zero

typedef _Float16 v8h __attribute__((ext_vector_type(8)));  // 8 fp16 (4 VGPRs)
typedef float v4f __attribute__((ext_vector_type(4)));     // mfma f32x4 acc

static const size_t OUT_ELEMS = (size_t)NB * 16 * NT * NF;  // 20,971,520

// ---------------------------------------------------------------------------
// conv3x3 SAME -> fp16 qkv [b][24][t][96], q channels (0..7) scaled by 0.25,
// f 80..95 zero-padded.
// ---------------------------------------------------------------------------
__global__ __launch_bounds__(256) void conv_in_k(
    const float* __restrict__ x, const float* __restrict__ w,
    const float* __restrict__ bias, _Float16* __restrict__ qkv) {
  __shared__ float xt[16][10][84];
  __shared__ float wt[24 * 144];
  __shared__ float bt[24];
  const int b = blockIdx.y, t0 = blockIdx.x * 8;
  const int tid = threadIdx.x;
  for (int i = tid; i < 24 * 144; i += 256) wt[i] = w[i];
  if (tid < 24) bt[tid] = bias[tid];
  for (int i = tid; i < 16 * 10 * 82; i += 256) {
    int c = i / 820, r = (i % 820) / 82, j = i % 82;
    int t = t0 + r - 1, f = j - 1;
    float v = 0.f;
    if (t >= 0 && t < NT && f >= 0 && f < NF)
      v = x[((size_t)(b * 16 + c) * NT + t) * NF + f];
    xt[c][r][j] = v;
  }
  __syncthreads();
  const int NTASK = 24 * 8 * 20;  // 4 consecutive f outputs per task
  for (int task = tid; task < NTASK; task += 256) {
    int oc = task / 160;
    int rem = task % 160;
    int tt = rem / 20;
    int fb = (rem % 20) * 4;
    float a0 = bt[oc], a1 = a0, a2 = a0, a3 = a0;
    for (int c = 0; c < 16; ++c) {
#pragma unroll
      for (int kt = 0; kt < 3; ++kt) {
        const float* wp = &wt[((oc * 16 + c) * 3 + kt) * 3];
        float w0 = wp[0], w1 = wp[1], w2 = wp[2];
        const float* xr = &xt[c][tt + kt][fb];
        float x0 = xr[0], x1 = xr[1], x2 = xr[2], x3 = xr[3], x4 = xr[4],
              x5 = xr[5];
        a0 += w0 * x0 + w1 * x1 + w2 * x2;
        a1 += w0 * x1 + w1 * x2 + w2 * x3;
        a2 += w0 * x2 + w1 * x3 + w2 * x4;
        a3 += w0 * x3 + w1 * x4 + w2 * x5;
      }
    }
    if (oc < 8) { a0 *= 0.25f; a1 *= 0.25f; a2 *= 0.25f; a3 *= 0.25f; }
    _Float16* op = qkv + ((size_t)(b * 24 + oc) * NT + t0 + tt) * FP + fb;
    op[0] = (_Float16)a0;
    op[1] = (_Float16)a1;
    op[2] = (_Float16)a2;
    op[3] = (_Float16)a3;
  }
  // zero pad f = 80..95
  for (int i = tid; i < 24 * 8; i += 256) {
    int oc = i / 8, tt = i % 8;
    int4 z = {0, 0, 0, 0};
    int4* p = (int4*)(qkv + ((size_t)(b * 24 + oc) * NT + t0 + tt) * FP + 80);
    p[0] = z;
    p[1] = z;
  }
}

// ---------------------------------------------------------------------------
// BN stats over fp16 qkv (pad zeros don't affect sums; N uses true 80 count).
// ---------------------------------------------------------------------------
__global__ __launch_bounds__(256) void bn_stats_h_k(
    const _Float16* __restrict__ x, float* __restrict__ partials) {
  const int b = blockIdx.x, c = blockIdx.y;
  const v8h* p = (const v8h*)(x + (size_t)(b * 24 + c) * NT * FP);
  float s = 0.f, s2 = 0.f;
  for (int i = threadIdx.x; i < NT * FP / 8; i += 256) {
    v8h v = p[i];
#pragma unroll
    for (int j = 0; j < 8; ++j) {
      float f = (float)v[j];
      s += f;
      s2 += f * f;
    }
  }
  __shared__ float rs[256], rs2[256];
  rs[threadIdx.x] = s;
  rs2[threadIdx.x] = s2;
  __syncthreads();
  for (int off = 128; off > 0; off >>= 1) {
    if ((int)threadIdx.x < off) {
      rs[threadIdx.x] += rs[threadIdx.x + off];
      rs2[threadIdx.x] += rs2[threadIdx.x + off];
    }
    __syncthreads();
  }
  if (threadIdx.x == 0) {
    partials[(c * 16 + b) * 2 + 0] = rs[0];
    partials[(c * 16 + b) * 2 + 1] = rs2[0];
  }
}

__global__ void bn_finalize_k(const float* __restrict__ partials,
                              float* __restrict__ stats, int C) {
  int c = threadIdx.x;
  if (c < C) {
    float s = 0.f, s2 = 0.f;
    for (int i = 0; i < 16; ++i) {
      s += partials[(c * 16 + i) * 2 + 0];
      s2 += partials[(c * 16 + i) * 2 + 1];
    }
    const float N = 16.0f * (float)(NT * NF);
    float mean = s / N;
    float var = s2 / N - mean * mean;
    stats[c * 2 + 0] = mean;
    stats[c * 2 + 1] = rsqrtf(var + 1e-5f);
  }
}

// BN affine + relu in place on fp16 qkv (skip pad chunks so they stay zero)
__global__ __launch_bounds__(256) void bn_apply_qkv_k(
    _Float16* __restrict__ qkv, const float* __restrict__ stats,
    const float* __restrict__ gq, const float* __restrict__ bq,
    const float* __restrict__ gk, const float* __restrict__ bk,
    const float* __restrict__ gv, const float* __restrict__ bv) {
  const size_t n8 = (size_t)NB * 24 * NT * 12;
  const size_t stride = (size_t)gridDim.x * blockDim.x;
  for (size_t idx = (size_t)blockIdx.x * blockDim.x + threadIdx.x; idx < n8;
       idx += stride) {
    int fc = (int)(idx % 12);
    if (fc >= 10) continue;  // f 80..95 stays zero
    int c = (int)((idx / (NT * 12)) % 24);
    float g, be;
    if (c < 8) { g = gq[c]; be = bq[c]; }
    else if (c < 16) { g = gk[c - 8]; be = bk[c - 8]; }
    else { g = gv[c - 16]; be = bv[c - 16]; }
    float mean = stats[c * 2 + 0], invstd = stats[c * 2 + 1];
    v8h v = ((v8h*)qkv)[idx];
#pragma unroll
    for (int j = 0; j < 8; ++j) {
      float f = (float)v[j];
      f = fmaxf((f - mean) * invstd * g + be, 0.f);
      v[j] = (_Float16)f;
    }
    ((v8h*)qkv)[idx] = v;
  }
}

// ---------------------------------------------------------------------------
// Time attention, MFMA fp16. Block = (16-query strip, b), 512 threads (8
// waves), loop h inside so aw head-sum accumulates in registers.
// PV B-fragments are gathered per-element from a V chunk staged in the SAME
// [256][96] row-major layout the QK^T K staging uses (no V transpose).
// ---------------------------------------------------------------------------
__global__ __launch_bounds__(512) void time_attn_k(
    const _Float16* __restrict__ qkv, float* __restrict__ attn_out,
    float* __restrict__ aw_avg) {
  __shared__ float s_lds[16][1024];                  // 64 KB: S/P strip, then O-reduce
  __shared__ _Float16 q_lds[16][FP];                 // 3 KB
  __shared__ __align__(16) _Float16 kstage[256 * FP];  // 48 KB: K / V chunks
  const int b = blockIdx.y, t0 = blockIdx.x * 16;
  const int tid = threadIdx.x;
  const int w = tid >> 6, l = tid & 63;
  const int lg = l >> 4, lm = l & 15;                // mfma frag coords
  const int grp = tid >> 5, lane = tid & 31;         // softmax coords
  float avg[32];
#pragma unroll
  for (int k = 0; k < 32; ++k) avg[k] = 0.f;

  for (int h = 0; h < NH; ++h) {
    const _Float16* qb = qkv + ((size_t)(b * 24 + h) * NT + t0) * FP;
    const _Float16* kb = qkv + (size_t)(b * 24 + 8 + h) * NT * FP;
    const _Float16* vb = qkv + (size_t)(b * 24 + 16 + h) * NT * FP;
    // ---- stage Q strip (contiguous 3 KB) ----
    if (tid < 192) ((int4*)q_lds)[tid] = ((const int4*)qb)[tid];
    __syncthreads();
    v8h afr[3];
#pragma unroll
    for (int kk = 0; kk < 3; ++kk)
      afr[kk] = *(const v8h*)&q_lds[lm][kk * 32 + lg * 8];
    // ---- S = Q K^T over 4 chunks of 256 keys ----
    for (int ck = 0; ck < 4; ++ck) {
      if (ck) __syncthreads();
      const int4* src = (const int4*)(kb + (size_t)ck * 256 * FP);
      for (int i = tid; i < 3072; i += 512) ((int4*)kstage)[i] = src[i];
      __syncthreads();
#pragma unroll
      for (int tt = 0; tt < 2; ++tt) {
        int rowb = (w * 2 + tt) * 16;
        v4f acc = {0.f, 0.f, 0.f, 0.f};
#pragma unroll
        for (int kk = 0; kk < 3; ++kk) {
          v8h bfr = *(const v8h*)&kstage[(rowb + lm) * FP + kk * 32 + lg * 8];
          acc = __builtin_amdgcn_mfma_f32_16x16x32_f16(afr[kk], bfr, acc, 0,
                                                       0, 0);
        }
        int sc = ck * 256 + rowb + lm;
#pragma unroll
        for (int r = 0; r < 4; ++r) s_lds[lg * 4 + r][sc] = acc[r];
      }
    }
    __syncthreads();
    // ---- softmax: row grp handled by 32 lanes ----
    float m = -1e30f;
#pragma unroll
    for (int k = 0; k < 32; ++k) m = fmaxf(m, s_lds[grp][lane + 32 * k]);
#pragma unroll
    for (int mk = 16; mk; mk >>= 1) m = fmaxf(m, __shfl_xor(m, mk, 32));
    float d = 0.f;
#pragma unroll
    for (int k = 0; k < 32; ++k) {
      float e = __expf(s_lds[grp][lane + 32 * k] - m);
      d += e;
      s_lds[grp][lane + 32 * k] = e;
    }
#pragma unroll
    for (int mk = 16; mk; mk >>= 1) d += __shfl_xor(d, mk, 32);
    float inv = 1.f / d;
#pragma unroll
    for (int k = 0; k < 32; ++k) {
      float p = s_lds[grp][lane + 32 * k] * inv;
      s_lds[grp][lane + 32 * k] = p;
      avg[k] += p;
    }
    __syncthreads();  // all P finalized
    // ---- O = P V over 4 chunks of 256 keys; wave w owns 32-key slice ----
    v4f accO[5];
#pragma unroll
    for (int ft = 0; ft < 5; ++ft) accO[ft] = (v4f){0.f, 0.f, 0.f, 0.f};
    for (int vc = 0; vc < 4; ++vc) {
      if (vc) __syncthreads();
      const int4* srcv = (const int4*)(vb + (size_t)vc * 256 * FP);
      for (int i = tid; i < 3072; i += 512) ((int4*)kstage)[i] = srcv[i];
      __syncthreads();
      // A = P fragment: row = lm (query), k = lg*8+j (key offset in wave slice)
      const float* pp = &s_lds[lm][vc * 256 + w * 32 + lg * 8];
      v8h pfr;
#pragma unroll
      for (int j = 0; j < 8; ++j) pfr[j] = (_Float16)pp[j];
#pragma unroll
      for (int ft = 0; ft < 5; ++ft) {
        // B = V fragment: col = lm (feature ft*16+lm), k = lg*8+j
        v8h bfr;
#pragma unroll
        for (int j = 0; j < 8; ++j)
          bfr[j] = kstage[(w * 32 + lg * 8 + j) * FP + ft * 16 + lm];
        accO[ft] =
            __builtin_amdgcn_mfma_f32_16x16x32_f16(pfr, bfr, accO[ft], 0, 0, 0);
      }
    }
    __syncthreads();
    // ---- cross-wave O reduce (s_lds reused; P dead) ----
    float* ored = (float*)s_lds;  // [8][16][80]
#pragma unroll
    for (int ft = 0; ft < 5; ++ft)
#pragma unroll
      for (int r = 0; r < 4; ++r)
        ored[(w * 16 + lg * 4 + r) * 80 + ft * 16 + lm] = accO[ft][r];
    __syncthreads();
    for (int i = tid; i < 1280; i += 512) {
      int q = i / 80, f = i % 80;
      float s = 0.f;
#pragma unroll
      for (int ww = 0; ww < 8; ++ww) s += ored[(ww * 16 + q) * 80 + f];
      attn_out[((size_t)(b * 16 + h) * NT + t0 + q) * NF + f] = s;
    }
    __syncthreads();
  }
  float* ab = aw_avg + ((size_t)b * NT + t0 + grp) * NT;
#pragma unroll
  for (int k = 0; k < 32; ++k) ab[lane + 32 * k] = avg[k] * 0.125f;
}

// ---------------------------------------------------------------------------
// Freq attention (scalar, fp16 inputs). Block per (b,h).
// ---------------------------------------------------------------------------
__global__ __launch_bounds__(256) void freq_attn_k(
    const _Float16* __restrict__ qkv, float* __restrict__ attn_out) {
  __shared__ float a_lds[64][FP];
  __shared__ float b_lds[64][FP];
  __shared__ float c_lds[80][81];
  const int bh = blockIdx.x;
  const int b = bh >> 3, h = bh & 7;
  const _Float16* qb = qkv + (size_t)(b * 24 + h) * NT * FP;
  const _Float16* kb = qkv + (size_t)(b * 24 + 8 + h) * NT * FP;
  const _Float16* vb = qkv + (size_t)(b * 24 + 16 + h) * NT * FP;
  const int tid = threadIdx.x;
  const int f0 = (tid & 15) * 5, g0 = (tid >> 4) * 5;
  float acc[5][5];
#pragma unroll
  for (int i = 0; i < 5; ++i)
#pragma unroll
    for (int j = 0; j < 5; ++j) acc[i][j] = 0.f;

  for (int tt = 0; tt < 16; ++tt) {
    int t0 = tt * 64;
    for (int i = tid; i < 64 * 12; i += 256) {
      int r = i / 12, c = i % 12;
      v8h va = *(const v8h*)(qb + (size_t)(t0 + r) * FP + c * 8);
      v8h vb2 = *(const v8h*)(kb + (size_t)(t0 + r) * FP + c * 8);
#pragma unroll
      for (int j = 0; j < 8; ++j) {
        a_lds[r][c * 8 + j] = (float)va[j];
        b_lds[r][c * 8 + j] = (float)vb2[j];
      }
    }
    __syncthreads();
    for (int r = 0; r < 64; ++r) {
      float qv[5], kv[5];
#pragma unroll
      for (int i = 0; i < 5; ++i) {
        qv[i] = a_lds[r][f0 + i];
        kv[i] = b_lds[r][g0 + i];
      }
#pragma unroll
      for (int i = 0; i < 5; ++i)
#pragma unroll
        for (int j = 0; j < 5; ++j) acc[i][j] += qv[i] * kv[j];
    }
    __syncthreads();
  }
#pragma unroll
  for (int i = 0; i < 5; ++i)
#pragma unroll
    for (int j = 0; j < 5; ++j) c_lds[f0 + i][g0 + j] = acc[i][j];
  __syncthreads();
  if (tid < 80) {
    float m = -1e30f;
    for (int g = 0; g < 80; ++g) m = fmaxf(m, c_lds[tid][g]);
    float dsum = 0.f;
    for (int g = 0; g < 80; ++g) {
      float e = __expf(c_lds[tid][g] - m);
      dsum += e;
      c_lds[tid][g] = e;
    }
    float invd = 1.f / dsum;
    for (int g = 0; g < 80; ++g) c_lds[tid][g] *= invd;
  }
  __syncthreads();
  float* ob = attn_out + (size_t)(b * 16 + 8 + h) * NT * NF;
  for (int vt = 0; vt < 16; ++vt) {
    int t0 = vt * 64;
    for (int i = tid; i < 64 * 12; i += 256) {
      int r = i / 12, c = i % 12;
      v8h vv = *(const v8h*)(vb + (size_t)(t0 + r) * FP + c * 8);
#pragma unroll
      for (int j = 0; j < 8; ++j) a_lds[r][c * 8 + j] = (float)vv[j];
    }
    __syncthreads();
    const int t = tid & 63;
    const int fg = tid >> 6;
    float oacc[20];
#pragma unroll
    for (int i = 0; i < 20; ++i) oacc[i] = 0.f;
    for (int g = 0; g < 80; ++g) {
      float vv = a_lds[t][g];
#pragma unroll
      for (int i = 0; i < 20; ++i) oacc[i] += vv * c_lds[fg * 20 + i][g];
    }
    float4* ob4 = (float4*)(ob + (size_t)(t0 + t) * NF + fg * 20);
#pragma unroll
    for (int m4 = 0; m4 < 5; ++m4)
      ob4[m4] = make_float4(oacc[4 * m4], oacc[4 * m4 + 1], oacc[4 * m4 + 2],
                            oacc[4 * m4 + 3]);
    __syncthreads();
  }
}

// ---------------------------------------------------------------------------
// conv3x3 fp32 (attn -> y), 16 in / 16 out channels
// ---------------------------------------------------------------------------
__global__ __launch_bounds__(256) void conv_out_k(
    const float* __restrict__ x, const float* __restrict__ w,
    const float* __restrict__ bias, float* __restrict__ out) {
  __shared__ float xt[16][10][84];
  __shared__ float wt[16 * 144];
  __shared__ float bt[16];
  const int b = blockIdx.y, t0 = blockIdx.x * 8;
  const int tid = threadIdx.x;
  for (int i = tid; i < 16 * 144; i += 256) wt[i] = w[i];
  if (tid < 16) bt[tid] = bias[tid];
  for (int i = tid; i < 16 * 10 * 82; i += 256) {
    int c = i / 820, r = (i % 820) / 82, j = i % 82;
    int t = t0 + r - 1, f = j - 1;
    float v = 0.f;
    if (t >= 0 && t < NT && f >= 0 && f < NF)
      v = x[((size_t)(b * 16 + c) * NT + t) * NF + f];
    xt[c][r][j] = v;
  }
  __syncthreads();
  const int NTASK = 16 * 8 * 20;
  for (int task = tid; task < NTASK; task += 256) {
    int oc = task / 160;
    int rem = task % 160;
    int tt = rem / 20;
    int fb = (rem % 20) * 4;
    float a0 = bt[oc], a1 = a0, a2 = a0, a3 = a0;
    for (int c = 0; c < 16; ++c) {
#pragma unroll
      for (int kt = 0; kt < 3; ++kt) {
        const float* wp = &wt[((oc * 16 + c) * 3 + kt) * 3];
        float w0 = wp[0], w1 = wp[1], w2 = wp[2];
        const float* xr = &xt[c][tt + kt][fb];
        float x0 = xr[0], x1 = xr[1], x2 = xr[2], x3 = xr[3], x4 = xr[4],
              x5 = xr[5];
        a0 += w0 * x0 + w1 * x1 + w2 * x2;
        a1 += w0 * x1 + w1 * x2 + w2 * x3;
        a2 += w0 * x2 + w1 * x3 + w2 * x4;
        a3 += w0 * x3 + w1 * x4 + w2 * x5;
      }
    }
    float* op = out + ((size_t)(b * 16 + oc) * NT + t0 + tt) * NF + fb;
    op[0] = a0; op[1] = a1; op[2] = a2; op[3] = a3;
  }
}

// BN stats fp32 (for y)
__global__ __launch_bounds__(256) void bn_stats_k(const float* __restrict__ x,
                                                  float* __restrict__ partials,
                                                  int C) {
  const int b = blockIdx.x, c = blockIdx.y;
  const float4* p = (const float4*)(x + (size_t)(b * C + c) * (NT * NF));
  float s = 0.f, s2 = 0.f;
  for (int i = threadIdx.x; i < (NT * NF) / 4; i += 256) {
    float4 v = p[i];
    s += v.x + v.y + v.z + v.w;
    s2 += v.x * v.x + v.y * v.y + v.z * v.z + v.w * v.w;
  }
  __shared__ float rs[256], rs2[256];
  rs[threadIdx.x] = s;
  rs2[threadIdx.x] = s2;
  __syncthreads();
  for (int off = 128; off > 0; off >>= 1) {
    if ((int)threadIdx.x < off) {
      rs[threadIdx.x] += rs[threadIdx.x + off];
      rs2[threadIdx.x] += rs2[threadIdx.x + off];
    }
    __syncthreads();
  }
  if (threadIdx.x == 0) {
    partials[(c * 16 + b) * 2 + 0] = rs[0];
    partials[(c * 16 + b) * 2 + 1] = rs2[0];
  }
}

__global__ __launch_bounds__(256) void bn_apply_out_k(
    const float* __restrict__ y, const float* __restrict__ stats,
    const float* __restrict__ go, const float* __restrict__ bo,
    float* __restrict__ out) {
  const size_t n4 = OUT_ELEMS / 4;
  const size_t stride = (size_t)gridDim.x * blockDim.x;
  for (size_t idx = (size_t)blockIdx.x * blockDim.x + threadIdx.x; idx < n4;
       idx += stride) {
    int c = (int)((idx / (NT * NF / 4)) % 16);
    float g = go[c], be = bo[c];
    float mean = stats[c * 2 + 0], invstd = stats[c * 2 + 1];
    float4 v = ((const float4*)y)[idx];
    v.x = fmaxf((v.x - mean) * invstd * g + be, 0.f);
    v.y = fmaxf((v.y - mean) * invstd * g + be, 0.f);
    v.z = fmaxf((v.z - mean) * invstd * g + be, 0.f);
    v.w = fmaxf((v.w - mean) * invstd * g + be, 0.f);
    ((float4*)out)[idx] = v;
  }
}

// ---------------------------------------------------------------------------
extern "C" void kernel_launch(void* const* d_in, const int* in_sizes, int n_in,
                              void* d_out, int out_size, void* d_ws,
                              size_t ws_size, hipStream_t stream) {
  const float* x = (const float*)d_in[0];
  const float* w_in = (const float*)d_in[1];
  const float* b_in = (const float*)d_in[2];
  const float* w_out = (const float*)d_in[3];
  const float* b_out = (const float*)d_in[4];
  const float* gq = (const float*)d_in[5];
  const float* bq = (const float*)d_in[6];
  const float* gk = (const float*)d_in[7];
  const float* bk = (const float*)d_in[8];
  const float* gv = (const float*)d_in[9];
  const float* bv = (const float*)d_in[10];
  const float* go = (const float*)d_in[11];
  const float* bo = (const float*)d_in[12];

  float* out = (float*)d_out;                         // (16,16,1024,80) fp32
  float* aw = out + OUT_ELEMS;                        // (16,1024,1024) fp32
  char* wsb = (char*)d_ws;
  _Float16* qkvb = (_Float16*)wsb;                    // 75,497,472 B
  float* y = (float*)wsb;                             // aliases qkvb when dead (83.9 MB)
  float* partials = (float*)(wsb + 104857600);        // +100 MiB: 768 floats
  float* stats1 = partials + 768;                     // 48
  float* stats2 = stats1 + 48;                        // 32

  conv_in_k<<<dim3(128, 16), 256, 0, stream>>>(x, w_in, b_in, qkvb);
  bn_stats_h_k<<<dim3(16, 24), 256, 0, stream>>>(qkvb, partials);
  bn_finalize_k<<<1, 64, 0, stream>>>(partials, stats1, 24);
  bn_apply_qkv_k<<<2048, 256, 0, stream>>>(qkvb, stats1, gq, bq, gk, bk, gv,
                                           bv);
  time_attn_k<<<dim3(64, 16), 512, 0, stream>>>(qkvb, out, aw);
  freq_attn_k<<<128, 256, 0, stream>>>(qkvb, out);
  conv_out_k<<<dim3(128, 16), 256, 0, stream>>>(out, w_out, b_out, y);
  bn_stats_k<<<dim3(16, 16), 256, 0, stream>>>(y, partials, 16);
  bn_finalize_k<<<1, 64, 0, stream>>>(partials, stats2, 16);
  bn_apply_out_k<<<4096, 256, 0, stream>>>(y, stats2, go, bo, out);
}

// Round 5
// 1138.134 us; speedup vs baseline: 5.2961x; 1.9013x over previous
//
#include <hip/hip_runtime.h>
#include <cstdint>
#include <cstddef>

// Problem constants: B=16, E=16, T=1024, F=80, H=8, 3H=24 qkv channels
#define NB 16
#define NT 1024
#define NF 80
#define NH 8
#define FP 96   // qkv f padded to 96 (3 x K=32 MFMA steps); pad is zero
#define FS 84   // channels-last padded f-sites (site s <-> f = s-1; 0,81..83 zero)

typedef _Float16 v8h __attribute__((ext_vector_type(8)));  // 8 fp16 (4 VGPRs)
typedef _Float16 v4h __attribute__((ext_vector_type(4)));  // 4 fp16 (8 B)
typedef float v4f __attribute__((ext_vector_type(4)));     // mfma f32x4 acc

static const size_t OUT_ELEMS = (size_t)NB * 16 * NT * NF;  // 20,971,520

// ---------------------------------------------------------------------------
// channels-last transpose: fp32 NCHW (16 ch) -> fp16 [b][t][84][16], sites
// 0 and 81..83 zeroed. Reads coalesced per channel, writes 32B contiguous.
// ---------------------------------------------------------------------------
__global__ __launch_bounds__(256) void cl_k(const float* __restrict__ src,
                                            _Float16* __restrict__ dst) {
  const int b = blockIdx.y, t0 = blockIdx.x * 16;
  for (int i = threadIdx.x; i < 16 * FS; i += 256) {
    int lt = i / FS, s = i % FS;
    int t = t0 + lt, f = s - 1;
    v8h lo = (v8h)(_Float16)0.f, hi = (v8h)(_Float16)0.f;
    if (f >= 0 && f < NF) {
#pragma unroll
      for (int c = 0; c < 8; ++c)
        lo[c] = (_Float16)src[((size_t)(b * 16 + c) * NT + t) * NF + f];
#pragma unroll
      for (int c = 0; c < 8; ++c)
        hi[c] = (_Float16)src[((size_t)(b * 16 + 8 + c) * NT + t) * NF + f];
    }
    _Float16* d = dst + ((size_t)(b * NT + t) * FS + s) * 16;
    *(v8h*)d = lo;
    *(v8h*)(d + 8) = hi;
  }
}

// ---------------------------------------------------------------------------
// conv3x3 SAME as MFMA implicit GEMM over channels-last fp16 input.
// A[fsite][k] = xrow[fsite*16 + k], k in [0,48) = (kf,c); per kt one GEMM.
// K split 32+16 (weight rows 48..63 zeroed). C[row=fsite][col=oc].
// OCT: oc 16-col tiles (2 -> CO=24 w/ lm<8 guard; 1 -> CO=16).
// ---------------------------------------------------------------------------
template <int OCT, int OSTRIDE, bool QSCALE, bool PADOUT>
__global__ __launch_bounds__(512) void conv_mfma_k(
    const _Float16* __restrict__ xcl, const float* __restrict__ w,
    const float* __restrict__ bias, _Float16* __restrict__ out, int CO) {
  __shared__ _Float16 axt[18][FS * 16];            // 48.4 KB
  __shared__ _Float16 wlds[3][2][OCT * 16][32];    // 12 / 6 KB
  __shared__ float blds[32];
  const int b = blockIdx.y, t0 = blockIdx.x * 16;
  const int tid = threadIdx.x;
  // ---- weights -> LDS (zero-padded in k>=48 and oc>=CO) ----
  const int NW = 3 * 2 * OCT * 16 * 32;
  for (int i = tid; i < NW; i += 512) {
    int kk = i % 32;
    int oc = (i / 32) % (OCT * 16);
    int ck = (i / (32 * OCT * 16)) % 2;
    int kt = i / (64 * OCT * 16);
    int kg = ck * 32 + kk;
    float v = 0.f;
    if (oc < CO && kg < 48) {
      int c = kg & 15, kf = kg >> 4;
      v = w[((oc * 16 + c) * 3 + kt) * 3 + kf];
      if (QSCALE && oc < 8) v *= 0.25f;
    }
    wlds[kt][ck][oc][kk] = (_Float16)v;
  }
  if (tid < 32) {
    float v = (tid < CO) ? bias[tid] : 0.f;
    if (QSCALE && tid < 8) v *= 0.25f;
    blds[tid] = v;
  }
  // ---- stage 18 channels-last input rows (t0-1 .. t0+16) ----
  for (int i = tid; i < 18 * 168; i += 512) {  // 168 int4 per 2688B row
    int r = i / 168, j = i % 168;
    int t = t0 + r - 1;
    int4 v = {0, 0, 0, 0};
    if (t >= 0 && t < NT)
      v = ((const int4*)(xcl + (size_t)(b * NT + t) * FS * 16))[j];
    ((int4*)axt[r])[j] = v;
  }
  __syncthreads();
  // ---- compute: wave -> 2 t-rows x 5 f-tiles ----
  const int wv = tid >> 6, l = tid & 63, lg = l >> 4, lm = l & 15;
  v8h bfr[3][2][OCT];
#pragma unroll
  for (int kt = 0; kt < 3; ++kt)
#pragma unroll
    for (int ck = 0; ck < 2; ++ck)
#pragma unroll
      for (int ot = 0; ot < OCT; ++ot)
        bfr[kt][ck][ot] = *(const v8h*)&wlds[kt][ck][ot * 16 + lm][lg * 8];
#pragma unroll
  for (int li = 0; li < 2; ++li) {
    const int lt = wv * 2 + li;
    const int tt = t0 + lt;
#pragma unroll
    for (int f0 = 0; f0 < 80; f0 += 16) {
      v4f acc[OCT];
#pragma unroll
      for (int ot = 0; ot < OCT; ++ot) acc[ot] = (v4f){0.f, 0.f, 0.f, 0.f};
#pragma unroll
      for (int kt = 0; kt < 3; ++kt)
#pragma unroll
        for (int ck = 0; ck < 2; ++ck) {
          v8h afr =
              *(const v8h*)&axt[lt + kt][(f0 + lm) * 16 + ck * 32 + lg * 8];
#pragma unroll
          for (int ot = 0; ot < OCT; ++ot)
            acc[ot] = __builtin_amdgcn_mfma_f32_16x16x32_f16(
                afr, bfr[kt][ck][ot], acc[ot], 0, 0, 0);
        }
#pragma unroll
      for (int ot = 0; ot < OCT; ++ot) {
        int oc = ot * 16 + lm;
        if (oc < CO) {
          float bv = blds[oc];
          v4h o;
#pragma unroll
          for (int r = 0; r < 4; ++r) o[r] = (_Float16)(acc[ot][r] + bv);
          *(v4h*)(out + ((size_t)(b * CO + oc) * NT + tt) * OSTRIDE + f0 +
                  lg * 4) = o;
        }
      }
    }
  }
  // ---- zero-pad output f in [80,96) (qkv layout only) ----
  if constexpr (PADOUT) {
    for (int i = tid; i < CO * 16 * 2; i += 512) {
      int oc = i / 32, lt2 = (i / 2) % 16, half = i & 1;
      int4 z = {0, 0, 0, 0};
      ((int4*)(out + ((size_t)(b * CO + oc) * NT + t0 + lt2) * OSTRIDE +
               80))[half] = z;
    }
  }
}

// ---------------------------------------------------------------------------
// BN stats over fp16 qkv [b][24][t][96] (pad zeros don't affect sums).
// ---------------------------------------------------------------------------
__global__ __launch_bounds__(256) void bn_stats_h_k(
    const _Float16* __restrict__ x, float* __restrict__ partials) {
  const int b = blockIdx.x, c = blockIdx.y;
  const v8h* p = (const v8h*)(x + (size_t)(b * 24 + c) * NT * FP);
  float s = 0.f, s2 = 0.f;
  for (int i = threadIdx.x; i < NT * FP / 8; i += 256) {
    v8h v = p[i];
#pragma unroll
    for (int j = 0; j < 8; ++j) {
      float f = (float)v[j];
      s += f;
      s2 += f * f;
    }
  }
  __shared__ float rs[256], rs2[256];
  rs[threadIdx.x] = s;
  rs2[threadIdx.x] = s2;
  __syncthreads();
  for (int off = 128; off > 0; off >>= 1) {
    if ((int)threadIdx.x < off) {
      rs[threadIdx.x] += rs[threadIdx.x + off];
      rs2[threadIdx.x] += rs2[threadIdx.x + off];
    }
    __syncthreads();
  }
  if (threadIdx.x == 0) {
    partials[(c * 16 + b) * 2 + 0] = rs[0];
    partials[(c * 16 + b) * 2 + 1] = rs2[0];
  }
}

// BN stats over fp16 y [b][16][t][80]
__global__ __launch_bounds__(256) void bn_stats_y_k(
    const _Float16* __restrict__ x, float* __restrict__ partials) {
  const int b = blockIdx.x, c = blockIdx.y;
  const v8h* p = (const v8h*)(x + (size_t)(b * 16 + c) * (NT * NF));
  float s = 0.f, s2 = 0.f;
  for (int i = threadIdx.x; i < NT * NF / 8; i += 256) {
    v8h v = p[i];
#pragma unroll
    for (int j = 0; j < 8; ++j) {
      float f = (float)v[j];
      s += f;
      s2 += f * f;
    }
  }
  __shared__ float rs[256], rs2[256];
  rs[threadIdx.x] = s;
  rs2[threadIdx.x] = s2;
  __syncthreads();
  for (int off = 128; off > 0; off >>= 1) {
    if ((int)threadIdx.x < off) {
      rs[threadIdx.x] += rs[threadIdx.x + off];
      rs2[threadIdx.x] += rs2[threadIdx.x + off];
    }
    __syncthreads();
  }
  if (threadIdx.x == 0) {
    partials[(c * 16 + b) * 2 + 0] = rs[0];
    partials[(c * 16 + b) * 2 + 1] = rs2[0];
  }
}

__global__ void bn_finalize_k(const float* __restrict__ partials,
                              float* __restrict__ stats, int C) {
  int c = threadIdx.x;
  if (c < C) {
    float s = 0.f, s2 = 0.f;
    for (int i = 0; i < 16; ++i) {
      s += partials[(c * 16 + i) * 2 + 0];
      s2 += partials[(c * 16 + i) * 2 + 1];
    }
    const float N = 16.0f * (float)(NT * NF);
    float mean = s / N;
    float var = s2 / N - mean * mean;
    stats[c * 2 + 0] = mean;
    stats[c * 2 + 1] = rsqrtf(var + 1e-5f);
  }
}

// BN affine + relu in place on fp16 qkv (skip pad chunks so they stay zero)
__global__ __launch_bounds__(256) void bn_apply_qkv_k(
    _Float16* __restrict__ qkv, const float* __restrict__ stats,
    const float* __restrict__ gq, const float* __restrict__ bq,
    const float* __restrict__ gk, const float* __restrict__ bk,
    const float* __restrict__ gv, const float* __restrict__ bv) {
  const size_t n8 = (size_t)NB * 24 * NT * 12;
  const size_t stride = (size_t)gridDim.x * blockDim.x;
  for (size_t idx = (size_t)blockIdx.x * blockDim.x + threadIdx.x; idx < n8;
       idx += stride) {
    int fc = (int)(idx % 12);
    if (fc >= 10) continue;  // f 80..95 stays zero
    int c = (int)((idx / (NT * 12)) % 24);
    float g, be;
    if (c < 8) { g = gq[c]; be = bq[c]; }
    else if (c < 16) { g = gk[c - 8]; be = bk[c - 8]; }
    else { g = gv[c - 16]; be = bv[c - 16]; }
    float mean = stats[c * 2 + 0], invstd = stats[c * 2 + 1];
    v8h v = ((v8h*)qkv)[idx];
#pragma unroll
    for (int j = 0; j < 8; ++j) {
      float f = (float)v[j];
      f = fmaxf((f - mean) * invstd * g + be, 0.f);
      v[j] = (_Float16)f;
    }
    ((v8h*)qkv)[idx] = v;
  }
}

// ---------------------------------------------------------------------------
// Time attention, MFMA fp16 (unchanged from round 4).
// ---------------------------------------------------------------------------
__global__ __launch_bounds__(512) void time_attn_k(
    const _Float16* __restrict__ qkv, float* __restrict__ attn_out,
    float* __restrict__ aw_avg) {
  __shared__ float s_lds[16][1024];                  // 64 KB
  __shared__ _Float16 q_lds[16][FP];                 // 3 KB
  __shared__ __align__(16) _Float16 kstage[256 * FP];  // 48 KB
  const int b = blockIdx.y, t0 = blockIdx.x * 16;
  const int tid = threadIdx.x;
  const int w = tid >> 6, l = tid & 63;
  const int lg = l >> 4, lm = l & 15;
  const int grp = tid >> 5, lane = tid & 31;
  float avg[32];
#pragma unroll
  for (int k = 0; k < 32; ++k) avg[k] = 0.f;

  for (int h = 0; h < NH; ++h) {
    const _Float16* qb = qkv + ((size_t)(b * 24 + h) * NT + t0) * FP;
    const _Float16* kb = qkv + (size_t)(b * 24 + 8 + h) * NT * FP;
    const _Float16* vb = qkv + (size_t)(b * 24 + 16 + h) * NT * FP;
    if (tid < 192) ((int4*)q_lds)[tid] = ((const int4*)qb)[tid];
    __syncthreads();
    v8h afr[3];
#pragma unroll
    for (int kk = 0; kk < 3; ++kk)
      afr[kk] = *(const v8h*)&q_lds[lm][kk * 32 + lg * 8];
    for (int ck = 0; ck < 4; ++ck) {
      if (ck) __syncthreads();
      const int4* src = (const int4*)(kb + (size_t)ck * 256 * FP);
      for (int i = tid; i < 3072; i += 512) ((int4*)kstage)[i] = src[i];
      __syncthreads();
#pragma unroll
      for (int tt = 0; tt < 2; ++tt) {
        int rowb = (w * 2 + tt) * 16;
        v4f acc = {0.f, 0.f, 0.f, 0.f};
#pragma unroll
        for (int kk = 0; kk < 3; ++kk) {
          v8h bfr = *(const v8h*)&kstage[(rowb + lm) * FP + kk * 32 + lg * 8];
          acc = __builtin_amdgcn_mfma_f32_16x16x32_f16(afr[kk], bfr, acc, 0,
                                                       0, 0);
        }
        int sc = ck * 256 + rowb + lm;
#pragma unroll
        for (int r = 0; r < 4; ++r) s_lds[lg * 4 + r][sc] = acc[r];
      }
    }
    __syncthreads();
    float m = -1e30f;
#pragma unroll
    for (int k = 0; k < 32; ++k) m = fmaxf(m, s_lds[grp][lane + 32 * k]);
#pragma unroll
    for (int mk = 16; mk; mk >>= 1) m = fmaxf(m, __shfl_xor(m, mk, 32));
    float d = 0.f;
#pragma unroll
    for (int k = 0; k < 32; ++k) {
      float e = __expf(s_lds[grp][lane + 32 * k] - m);
      d += e;
      s_lds[grp][lane + 32 * k] = e;
    }
#pragma unroll
    for (int mk = 16; mk; mk >>= 1) d += __shfl_xor(d, mk, 32);
    float inv = 1.f / d;
#pragma unroll
    for (int k = 0; k < 32; ++k) {
      float p = s_lds[grp][lane + 32 * k] * inv;
      s_lds[grp][lane + 32 * k] = p;
      avg[k] += p;
    }
    __syncthreads();
    v4f accO[5];
#pragma unroll
    for (int ft = 0; ft < 5; ++ft) accO[ft] = (v4f){0.f, 0.f, 0.f, 0.f};
    for (int vc = 0; vc < 4; ++vc) {
      if (vc) __syncthreads();
      const int4* srcv = (const int4*)(vb + (size_t)vc * 256 * FP);
      for (int i = tid; i < 3072; i += 512) ((int4*)kstage)[i] = srcv[i];
      __syncthreads();
      const float* pp = &s_lds[lm][vc * 256 + w * 32 + lg * 8];
      v8h pfr;
#pragma unroll
      for (int j = 0; j < 8; ++j) pfr[j] = (_Float16)pp[j];
#pragma unroll
      for (int ft = 0; ft < 5; ++ft) {
        v8h bfr;
#pragma unroll
        for (int j = 0; j < 8; ++j)
          bfr[j] = kstage[(w * 32 + lg * 8 + j) * FP + ft * 16 + lm];
        accO[ft] =
            __builtin_amdgcn_mfma_f32_16x16x32_f16(pfr, bfr, accO[ft], 0, 0, 0);
      }
    }
    __syncthreads();
    float* ored = (float*)s_lds;  // [8][16][80]
#pragma unroll
    for (int ft = 0; ft < 5; ++ft)
#pragma unroll
      for (int r = 0; r < 4; ++r)
        ored[(w * 16 + lg * 4 + r) * 80 + ft * 16 + lm] = accO[ft][r];
    __syncthreads();
    for (int i = tid; i < 1280; i += 512) {
      int q = i / 80, f = i % 80;
      float s = 0.f;
#pragma unroll
      for (int ww = 0; ww < 8; ++ww) s += ored[(ww * 16 + q) * 80 + f];
      attn_out[((size_t)(b * 16 + h) * NT + t0 + q) * NF + f] = s;
    }
    __syncthreads();
  }
  float* ab = aw_avg + ((size_t)b * NT + t0 + grp) * NT;
#pragma unroll
  for (int k = 0; k < 32; ++k) ab[lane + 32 * k] = avg[k] * 0.125f;
}

// ---------------------------------------------------------------------------
// Freq attention (scalar, fp16 inputs; unchanged from round 4).
// ---------------------------------------------------------------------------
__global__ __launch_bounds__(256) void freq_attn_k(
    const _Float16* __restrict__ qkv, float* __restrict__ attn_out) {
  __shared__ float a_lds[64][FP];
  __shared__ float b_lds[64][FP];
  __shared__ float c_lds[80][81];
  const int bh = blockIdx.x;
  const int b = bh >> 3, h = bh & 7;
  const _Float16* qb = qkv + (size_t)(b * 24 + h) * NT * FP;
  const _Float16* kb = qkv + (size_t)(b * 24 + 8 + h) * NT * FP;
  const _Float16* vb = qkv + (size_t)(b * 24 + 16 + h) * NT * FP;
  const int tid = threadIdx.x;
  const int f0 = (tid & 15) * 5, g0 = (tid >> 4) * 5;
  float acc[5][5];
#pragma unroll
  for (int i = 0; i < 5; ++i)
#pragma unroll
    for (int j = 0; j < 5; ++j) acc[i][j] = 0.f;

  for (int tt = 0; tt < 16; ++tt) {
    int t0 = tt * 64;
    for (int i = tid; i < 64 * 12; i += 256) {
      int r = i / 12, c = i % 12;
      v8h va = *(const v8h*)(qb + (size_t)(t0 + r) * FP + c * 8);
      v8h vb2 = *(const v8h*)(kb + (size_t)(t0 + r) * FP + c * 8);
#pragma unroll
      for (int j = 0; j < 8; ++j) {
        a_lds[r][c * 8 + j] = (float)va[j];
        b_lds[r][c * 8 + j] = (float)vb2[j];
      }
    }
    __syncthreads();
    for (int r = 0; r < 64; ++r) {
      float qv[5], kv[5];
#pragma unroll
      for (int i = 0; i < 5; ++i) {
        qv[i] = a_lds[r][f0 + i];
        kv[i] = b_lds[r][g0 + i];
      }
#pragma unroll
      for (int i = 0; i < 5; ++i)
#pragma unroll
        for (int j = 0; j < 5; ++j) acc[i][j] += qv[i] * kv[j];
    }
    __syncthreads();
  }
#pragma unroll
  for (int i = 0; i < 5; ++i)
#pragma unroll
    for (int j = 0; j < 5; ++j) c_lds[f0 + i][g0 + j] = acc[i][j];
  __syncthreads();
  if (tid < 80) {
    float m = -1e30f;
    for (int g = 0; g < 80; ++g) m = fmaxf(m, c_lds[tid][g]);
    float dsum = 0.f;
    for (int g = 0; g < 80; ++g) {
      float e = __expf(c_lds[tid][g] - m);
      dsum += e;
      c_lds[tid][g] = e;
    }
    float invd = 1.f / dsum;
    for (int g = 0; g < 80; ++g) c_lds[tid][g] *= invd;
  }
  __syncthreads();
  float* ob = attn_out + (size_t)(b * 16 + 8 + h) * NT * NF;
  for (int vt = 0; vt < 16; ++vt) {
    int t0 = vt * 64;
    for (int i = tid; i < 64 * 12; i += 256) {
      int r = i / 12, c = i % 12;
      v8h vv = *(const v8h*)(vb + (size_t)(t0 + r) * FP + c * 8);
#pragma unroll
      for (int j = 0; j < 8; ++j) a_lds[r][c * 8 + j] = (float)vv[j];
    }
    __syncthreads();
    const int t = tid & 63;
    const int fg = tid >> 6;
    float oacc[20];
#pragma unroll
    for (int i = 0; i < 20; ++i) oacc[i] = 0.f;
    for (int g = 0; g < 80; ++g) {
      float vv = a_lds[t][g];
#pragma unroll
      for (int i = 0; i < 20; ++i) oacc[i] += vv * c_lds[fg * 20 + i][g];
    }
    float4* ob4 = (float4*)(ob + (size_t)(t0 + t) * NF + fg * 20);
#pragma unroll
    for (int m4 = 0; m4 < 5; ++m4)
      ob4[m4] = make_float4(oacc[4 * m4], oacc[4 * m4 + 1], oacc[4 * m4 + 2],
                            oacc[4 * m4 + 3]);
    __syncthreads();
  }
}

// BN + relu: read fp16 y, write final fp32 out
__global__ __launch_bounds__(256) void bn_apply_out_k(
    const _Float16* __restrict__ y, const float* __restrict__ stats,
    const float* __restrict__ go, const float* __restrict__ bo,
    float* __restrict__ out) {
  const size_t n8 = OUT_ELEMS / 8;
  const size_t stride = (size_t)gridDim.x * blockDim.x;
  for (size_t idx = (size_t)blockIdx.x * blockDim.x + threadIdx.x; idx < n8;
       idx += stride) {
    int c = (int)((idx / (NT * NF / 8)) % 16);
    float g = go[c], be = bo[c];
    float mean = stats[c * 2 + 0], invstd = stats[c * 2 + 1];
    v8h v = ((const v8h*)y)[idx];
    float4 o0, o1;
    o0.x = fmaxf(((float)v[0] - mean) * invstd * g + be, 0.f);
    o0.y = fmaxf(((float)v[1] - mean) * invstd * g + be, 0.f);
    o0.z = fmaxf(((float)v[2] - mean) * invstd * g + be, 0.f);
    o0.w = fmaxf(((float)v[3] - mean) * invstd * g + be, 0.f);
    o1.x = fmaxf(((float)v[4] - mean) * invstd * g + be, 0.f);
    o1.y = fmaxf(((float)v[5] - mean) * invstd * g + be, 0.f);
    o1.z = fmaxf(((float)v[6] - mean) * invstd * g + be, 0.f);
    o1.w = fmaxf(((float)v[7] - mean) * invstd * g + be, 0.f);
    ((float4*)out)[idx * 2] = o0;
    ((float4*)out)[idx * 2 + 1] = o1;
  }
}

// ---------------------------------------------------------------------------
extern "C" void kernel_launch(void* const* d_in, const int* in_sizes, int n_in,
                              void* d_out, int out_size, void* d_ws,
                              size_t ws_size, hipStream_t stream) {
  const float* x = (const float*)d_in[0];
  const float* w_in = (const float*)d_in[1];
  const float* b_in = (const float*)d_in[2];
  const float* w_out = (const float*)d_in[3];
  const float* b_out = (const float*)d_in[4];
  const float* gq = (const float*)d_in[5];
  const float* bq = (const float*)d_in[6];
  const float* gk = (const float*)d_in[7];
  const float* bk = (const float*)d_in[8];
  const float* gv = (const float*)d_in[9];
  const float* bv = (const float*)d_in[10];
  const float* go = (const float*)d_in[11];
  const float* bo = (const float*)d_in[12];

  float* out = (float*)d_out;                    // (16,16,1024,80) fp32
  float* aw = out + OUT_ELEMS;                   // (16,1024,1024) fp32
  char* wsb = (char*)d_ws;
  _Float16* qkvb = (_Float16*)wsb;               // [0, 75,497,472)
  _Float16* yh = (_Float16*)wsb;                 // fp16 y aliases dead qkvb (41.9 MB)
  _Float16* xcl = (_Float16*)(wsb + 75497472);   // [75.5 MB, 119.5 MB) (44,040,192)
  _Float16* acl = xcl;                           // reuses xcl region (xcl dead)
  float* partials = (float*)(wsb + 119537664);   // 768 floats
  float* stats1 = partials + 768;                // 48
  float* stats2 = stats1 + 48;                   // 32

  // conv_in as MFMA implicit GEMM (+ folded q scaling)
  cl_k<<<dim3(64, 16), 256, 0, stream>>>(x, xcl);
  conv_mfma_k<2, FP, true, true>
      <<<dim3(64, 16), 512, 0, stream>>>(xcl, w_in, b_in, qkvb, 24);
  // BN + relu on qkv
  bn_stats_h_k<<<dim3(16, 24), 256, 0, stream>>>(qkvb, partials);
  bn_finalize_k<<<1, 64, 0, stream>>>(partials, stats1, 24);
  bn_apply_qkv_k<<<2048, 256, 0, stream>>>(qkvb, stats1, gq, bq, gk, bk, gv,
                                           bv);
  // attention; attn tensor staged fp32 in the `out` region of d_out
  time_attn_k<<<dim3(64, 16), 512, 0, stream>>>(qkvb, out, aw);
  freq_attn_k<<<128, 256, 0, stream>>>(qkvb, out);
  // conv_out as MFMA implicit GEMM (attn -> channels-last -> fp16 y)
  cl_k<<<dim3(64, 16), 256, 0, stream>>>(out, acl);
  conv_mfma_k<1, NF, false, false>
      <<<dim3(64, 16), 512, 0, stream>>>(acl, w_out, b_out, yh, 16);
  // final BN + relu -> out
  bn_stats_y_k<<<dim3(16, 16), 256, 0, stream>>>(yh, partials);
  bn_finalize_k<<<1, 64, 0, stream>>>(partials, stats2, 16);
  bn_apply_out_k<<<2048, 256, 0, stream>>>(yh, stats2, go, bo, out);
}

// Round 6
// 652.128 us; speedup vs baseline: 9.2430x; 1.7453x over previous
//
#include <hip/hip_runtime.h>
#include <cstdint>
#include <cstddef>

// Problem constants: B=16, E=16, T=1024, F=80, H=8, 3H=24 qkv channels
#define NB 16
#define NT 1024
#define NF 80
#define NH 8
#define FP 96   // qkv f padded to 96 (3 x K=32 MFMA steps); pad is zero
#define FS 84   // channels-last padded f-sites (site s <-> f = s-1; 0,81..83 zero)
#define SP 1032 // time_attn S-strip row stride (fp16)
#define KP 108  // time_attn kst/q_lds row stride (fp16); 216 B (8B aligned, odd*8)

typedef _Float16 v8h __attribute__((ext_vector_type(8)));  // 8 fp16 (4 VGPRs)
typedef _Float16 v4h __attribute__((ext_vector_type(4)));  // 4 fp16 (8 B)
typedef _Float16 v2h __attribute__((ext_vector_type(2)));  // 2 fp16 (4 B)
typedef float v4f __attribute__((ext_vector_type(4)));     // mfma f32x4 acc

static const size_t OUT_ELEMS = (size_t)NB * 16 * NT * NF;  // 20,971,520

// ---------------------------------------------------------------------------
// channels-last transpose: fp32 NCHW (16 ch) -> fp16 [b][t][84][16], sites
// 0 and 81..83 zeroed.
// ---------------------------------------------------------------------------
__global__ __launch_bounds__(256) void cl_k(const float* __restrict__ src,
                                            _Float16* __restrict__ dst) {
  const int b = blockIdx.y, t0 = blockIdx.x * 16;
  for (int i = threadIdx.x; i < 16 * FS; i += 256) {
    int lt = i / FS, s = i % FS;
    int t = t0 + lt, f = s - 1;
    v8h lo = (v8h)(_Float16)0.f, hi = (v8h)(_Float16)0.f;
    if (f >= 0 && f < NF) {
#pragma unroll
      for (int c = 0; c < 8; ++c)
        lo[c] = (_Float16)src[((size_t)(b * 16 + c) * NT + t) * NF + f];
#pragma unroll
      for (int c = 0; c < 8; ++c)
        hi[c] = (_Float16)src[((size_t)(b * 16 + 8 + c) * NT + t) * NF + f];
    }
    _Float16* d = dst + ((size_t)(b * NT + t) * FS + s) * 16;
    *(v8h*)d = lo;
    *(v8h*)(d + 8) = hi;
  }
}

// ---------------------------------------------------------------------------
// conv3x3 SAME as MFMA implicit GEMM over channels-last fp16 input.
// ---------------------------------------------------------------------------
template <int OCT, int OSTRIDE, bool QSCALE, bool PADOUT>
__global__ __launch_bounds__(512) void conv_mfma_k(
    const _Float16* __restrict__ xcl, const float* __restrict__ w,
    const float* __restrict__ bias, _Float16* __restrict__ out, int CO) {
  __shared__ _Float16 axt[18][FS * 16];            // 48.4 KB
  __shared__ _Float16 wlds[3][2][OCT * 16][32];    // 12 / 6 KB
  __shared__ float blds[32];
  const int b = blockIdx.y, t0 = blockIdx.x * 16;
  const int tid = threadIdx.x;
  const int NW = 3 * 2 * OCT * 16 * 32;
  for (int i = tid; i < NW; i += 512) {
    int kk = i % 32;
    int oc = (i / 32) % (OCT * 16);
    int ck = (i / (32 * OCT * 16)) % 2;
    int kt = i / (64 * OCT * 16);
    int kg = ck * 32 + kk;
    float v = 0.f;
    if (oc < CO && kg < 48) {
      int c = kg & 15, kf = kg >> 4;
      v = w[((oc * 16 + c) * 3 + kt) * 3 + kf];
      if (QSCALE && oc < 8) v *= 0.25f;
    }
    wlds[kt][ck][oc][kk] = (_Float16)v;
  }
  if (tid < 32) {
    float v = (tid < CO) ? bias[tid] : 0.f;
    if (QSCALE && tid < 8) v *= 0.25f;
    blds[tid] = v;
  }
  for (int i = tid; i < 18 * 168; i += 512) {
    int r = i / 168, j = i % 168;
    int t = t0 + r - 1;
    int4 v = {0, 0, 0, 0};
    if (t >= 0 && t < NT)
      v = ((const int4*)(xcl + (size_t)(b * NT + t) * FS * 16))[j];
    ((int4*)axt[r])[j] = v;
  }
  __syncthreads();
  const int wv = tid >> 6, l = tid & 63, lg = l >> 4, lm = l & 15;
  v8h bfr[3][2][OCT];
#pragma unroll
  for (int kt = 0; kt < 3; ++kt)
#pragma unroll
    for (int ck = 0; ck < 2; ++ck)
#pragma unroll
      for (int ot = 0; ot < OCT; ++ot)
        bfr[kt][ck][ot] = *(const v8h*)&wlds[kt][ck][ot * 16 + lm][lg * 8];
#pragma unroll
  for (int li = 0; li < 2; ++li) {
    const int lt = wv * 2 + li;
    const int tt = t0 + lt;
#pragma unroll
    for (int f0 = 0; f0 < 80; f0 += 16) {
      v4f acc[OCT];
#pragma unroll
      for (int ot = 0; ot < OCT; ++ot) acc[ot] = (v4f){0.f, 0.f, 0.f, 0.f};
#pragma unroll
      for (int kt = 0; kt < 3; ++kt)
#pragma unroll
        for (int ck = 0; ck < 2; ++ck) {
          v8h afr =
              *(const v8h*)&axt[lt + kt][(f0 + lm) * 16 + ck * 32 + lg * 8];
#pragma unroll
          for (int ot = 0; ot < OCT; ++ot)
            acc[ot] = __builtin_amdgcn_mfma_f32_16x16x32_f16(
                afr, bfr[kt][ck][ot], acc[ot], 0, 0, 0);
        }
#pragma unroll
      for (int ot = 0; ot < OCT; ++ot) {
        int oc = ot * 16 + lm;
        if (oc < CO) {
          float bv = blds[oc];
          v4h o;
#pragma unroll
          for (int r = 0; r < 4; ++r) o[r] = (_Float16)(acc[ot][r] + bv);
          *(v4h*)(out + ((size_t)(b * CO + oc) * NT + tt) * OSTRIDE + f0 +
                  lg * 4) = o;
        }
      }
    }
  }
  if constexpr (PADOUT) {
    for (int i = tid; i < CO * 16 * 2; i += 512) {
      int oc = i / 32, lt2 = (i / 2) % 16, half = i & 1;
      int4 z = {0, 0, 0, 0};
      ((int4*)(out + ((size_t)(b * CO + oc) * NT + t0 + lt2) * OSTRIDE +
               80))[half] = z;
    }
  }
}

// ---------------------------------------------------------------------------
// BN stats over fp16 qkv [b][24][t][96]
// ---------------------------------------------------------------------------
__global__ __launch_bounds__(256) void bn_stats_h_k(
    const _Float16* __restrict__ x, float* __restrict__ partials) {
  const int b = blockIdx.x, c = blockIdx.y;
  const v8h* p = (const v8h*)(x + (size_t)(b * 24 + c) * NT * FP);
  float s = 0.f, s2 = 0.f;
  for (int i = threadIdx.x; i < NT * FP / 8; i += 256) {
    v8h v = p[i];
#pragma unroll
    for (int j = 0; j < 8; ++j) {
      float f = (float)v[j];
      s += f;
      s2 += f * f;
    }
  }
  __shared__ float rs[256], rs2[256];
  rs[threadIdx.x] = s;
  rs2[threadIdx.x] = s2;
  __syncthreads();
  for (int off = 128; off > 0; off >>= 1) {
    if ((int)threadIdx.x < off) {
      rs[threadIdx.x] += rs[threadIdx.x + off];
      rs2[threadIdx.x] += rs2[threadIdx.x + off];
    }
    __syncthreads();
  }
  if (threadIdx.x == 0) {
    partials[(c * 16 + b) * 2 + 0] = rs[0];
    partials[(c * 16 + b) * 2 + 1] = rs2[0];
  }
}

// BN stats over fp16 y [b][16][t][80]
__global__ __launch_bounds__(256) void bn_stats_y_k(
    const _Float16* __restrict__ x, float* __restrict__ partials) {
  const int b = blockIdx.x, c = blockIdx.y;
  const v8h* p = (const v8h*)(x + (size_t)(b * 16 + c) * (NT * NF));
  float s = 0.f, s2 = 0.f;
  for (int i = threadIdx.x; i < NT * NF / 8; i += 256) {
    v8h v = p[i];
#pragma unroll
    for (int j = 0; j < 8; ++j) {
      float f = (float)v[j];
      s += f;
      s2 += f * f;
    }
  }
  __shared__ float rs[256], rs2[256];
  rs[threadIdx.x] = s;
  rs2[threadIdx.x] = s2;
  __syncthreads();
  for (int off = 128; off > 0; off >>= 1) {
    if ((int)threadIdx.x < off) {
      rs[threadIdx.x] += rs[threadIdx.x + off];
      rs2[threadIdx.x] += rs2[threadIdx.x + off];
    }
    __syncthreads();
  }
  if (threadIdx.x == 0) {
    partials[(c * 16 + b) * 2 + 0] = rs[0];
    partials[(c * 16 + b) * 2 + 1] = rs2[0];
  }
}

__global__ void bn_finalize_k(const float* __restrict__ partials,
                              float* __restrict__ stats, int C) {
  int c = threadIdx.x;
  if (c < C) {
    float s = 0.f, s2 = 0.f;
    for (int i = 0; i < 16; ++i) {
      s += partials[(c * 16 + i) * 2 + 0];
      s2 += partials[(c * 16 + i) * 2 + 1];
    }
    const float N = 16.0f * (float)(NT * NF);
    float mean = s / N;
    float var = s2 / N - mean * mean;
    stats[c * 2 + 0] = mean;
    stats[c * 2 + 1] = rsqrtf(var + 1e-5f);
  }
}

// BN affine + relu in place on fp16 qkv
__global__ __launch_bounds__(256) void bn_apply_qkv_k(
    _Float16* __restrict__ qkv, const float* __restrict__ stats,
    const float* __restrict__ gq, const float* __restrict__ bq,
    const float* __restrict__ gk, const float* __restrict__ bk,
    const float* __restrict__ gv, const float* __restrict__ bv) {
  const size_t n8 = (size_t)NB * 24 * NT * 12;
  const size_t stride = (size_t)gridDim.x * blockDim.x;
  for (size_t idx = (size_t)blockIdx.x * blockDim.x + threadIdx.x; idx < n8;
       idx += stride) {
    int fc = (int)(idx % 12);
    if (fc >= 10) continue;  // f 80..95 stays zero
    int c = (int)((idx / (NT * 12)) % 24);
    float g, be;
    if (c < 8) { g = gq[c]; be = bq[c]; }
    else if (c < 16) { g = gk[c - 8]; be = bk[c - 8]; }
    else { g = gv[c - 16]; be = bv[c - 16]; }
    float mean = stats[c * 2 + 0], invstd = stats[c * 2 + 1];
    v8h v = ((v8h*)qkv)[idx];
#pragma unroll
    for (int j = 0; j < 8; ++j) {
      float f = (float)v[j];
      f = fmaxf((f - mean) * invstd * g + be, 0.f);
      v[j] = (_Float16)f;
    }
    ((v8h*)qkv)[idx] = v;
  }
}

// ---------------------------------------------------------------------------
// Time attention, MFMA fp16. Block = (32-query strip, b), 512 threads.
// Register-staged prefetch pipeline over chunk stream K0..K3,V0..V3.
// S strip kept fp16 (unnormalized e after softmax; O scaled by inv at end).
// ---------------------------------------------------------------------------
__global__ __launch_bounds__(512) void time_attn_k(
    const _Float16* __restrict__ qkv, float* __restrict__ attn_out,
    float* __restrict__ aw_avg) {
  __shared__ _Float16 s_lds[32 * SP];   // 66 KB; reused as ored fp32 [8][16][84]
  __shared__ _Float16 q_lds[32 * KP];   // 6.9 KB
  __shared__ _Float16 kst[256 * KP];    // 55.3 KB (K / V chunks, padded rows)
  __shared__ float inv_lds[32];
  const int b = blockIdx.y, t0 = blockIdx.x * 32;
  const int tid = threadIdx.x;
  const int w = tid >> 6, l = tid & 63, lg = l >> 4, lm = l & 15;
  const int grp = tid >> 5, lane = tid & 31;
  float avg[2][32];
#pragma unroll
  for (int rr = 0; rr < 2; ++rr)
#pragma unroll
    for (int k = 0; k < 32; ++k) avg[rr][k] = 0.f;

  int4 rb[6];
  auto gload = [&](const _Float16* base, int chunk) {
    const int4* src = (const int4*)(base + (size_t)chunk * 256 * FP);
#pragma unroll
    for (int u = 0; u < 6; ++u) rb[u] = src[tid + u * 512];
  };
  auto lwrite = [&]() {
#pragma unroll
    for (int u = 0; u < 6; ++u) {
      int i = tid + u * 512, row = i / 12, j = i % 12;
      int2* d = (int2*)&kst[row * KP + j * 8];
      d[0] = make_int2(rb[u].x, rb[u].y);
      d[1] = make_int2(rb[u].z, rb[u].w);
    }
  };

  // preload first head's K chunk 0
  gload(qkv + (size_t)(b * 24 + 8) * NT * FP, 0);

  for (int h = 0; h < NH; ++h) {
    const _Float16* qb = qkv + ((size_t)(b * 24 + h) * NT + t0) * FP;
    const _Float16* kb = qkv + (size_t)(b * 24 + 8 + h) * NT * FP;
    const _Float16* vb = qkv + (size_t)(b * 24 + 16 + h) * NT * FP;
    // Q strip -> regs (32 rows x 12 int4)
    int4 qreg = {0, 0, 0, 0};
    if (tid < 384) qreg = ((const int4*)qb)[tid];
    lwrite();  // K0 -> kst
    if (tid < 384) {
      int row = tid / 12, j = tid % 12;
      int2* d = (int2*)&q_lds[row * KP + j * 8];
      d[0] = make_int2(qreg.x, qreg.y);
      d[1] = make_int2(qreg.z, qreg.w);
    }
    gload(kb, 1);
    __syncthreads();
    // A fragments (Q) for both query tiles
    v8h afr[2][3];
#pragma unroll
    for (int qt = 0; qt < 2; ++qt)
#pragma unroll
      for (int kk = 0; kk < 3; ++kk) {
        v4h a0 = *(const v4h*)&q_lds[(qt * 16 + lm) * KP + kk * 32 + lg * 8];
        v4h a1 =
            *(const v4h*)&q_lds[(qt * 16 + lm) * KP + kk * 32 + lg * 8 + 4];
        afr[qt][kk] = __builtin_shufflevector(a0, a1, 0, 1, 2, 3, 4, 5, 6, 7);
      }
    v4f accO[2][5];
#pragma unroll
    for (int qt = 0; qt < 2; ++qt)
#pragma unroll
      for (int ft = 0; ft < 5; ++ft) accO[qt][ft] = (v4f){0.f, 0.f, 0.f, 0.f};

    for (int s = 0; s < 8; ++s) {
      if (s == 4) {
        // ---- softmax on rows grp, grp+16 (S complete; own-row access) ----
#pragma unroll
        for (int rr = 0; rr < 2; ++rr) {
          const int row = grp + rr * 16;
          _Float16* srow = &s_lds[row * SP];
          float m = -1e30f;
#pragma unroll
          for (int k = 0; k < 16; ++k) {
            v2h e2 = *(const v2h*)&srow[lane * 2 + k * 64];
            m = fmaxf(m, fmaxf((float)e2[0], (float)e2[1]));
          }
#pragma unroll
          for (int mk = 16; mk; mk >>= 1) m = fmaxf(m, __shfl_xor(m, mk, 32));
          float d = 0.f;
#pragma unroll
          for (int k = 0; k < 16; ++k) {
            v2h e2 = *(const v2h*)&srow[lane * 2 + k * 64];
            float e0 = __expf((float)e2[0] - m);
            float e1 = __expf((float)e2[1] - m);
            d += e0 + e1;
            v2h w2;
            w2[0] = (_Float16)e0;
            w2[1] = (_Float16)e1;
            *(v2h*)&srow[lane * 2 + k * 64] = w2;
          }
#pragma unroll
          for (int mk = 16; mk; mk >>= 1) d += __shfl_xor(d, mk, 32);
          float inv = 1.f / d;
          if (lane == 0) inv_lds[row] = inv;
#pragma unroll
          for (int k = 0; k < 16; ++k) {
            v2h e2 = *(const v2h*)&srow[lane * 2 + k * 64];
            avg[rr][2 * k] += (float)e2[0] * inv;
            avg[rr][2 * k + 1] += (float)e2[1] * inv;
          }
        }
        __syncthreads();  // P final before cross-row PV reads
      }
      if (s < 4) {
        // ---- QK on kst = K chunk s ----
#pragma unroll
        for (int tt = 0; tt < 2; ++tt) {
          const int rowb = (w * 2 + tt) * 16;
          const int rbase = (rowb + lm) * KP;
          v8h bfr[3];
#pragma unroll
          for (int kk = 0; kk < 3; ++kk) {
            v4h b0 = *(const v4h*)&kst[rbase + kk * 32 + lg * 8];
            v4h b1 = *(const v4h*)&kst[rbase + kk * 32 + lg * 8 + 4];
            bfr[kk] = __builtin_shufflevector(b0, b1, 0, 1, 2, 3, 4, 5, 6, 7);
          }
          const int sc = s * 256 + rowb + lm;
#pragma unroll
          for (int qt = 0; qt < 2; ++qt) {
            v4f acc = (v4f){0.f, 0.f, 0.f, 0.f};
#pragma unroll
            for (int kk = 0; kk < 3; ++kk)
              acc = __builtin_amdgcn_mfma_f32_16x16x32_f16(afr[qt][kk],
                                                           bfr[kk], acc, 0, 0,
                                                           0);
#pragma unroll
            for (int r = 0; r < 4; ++r)
              s_lds[(qt * 16 + lg * 4 + r) * SP + sc] = (_Float16)acc[r];
          }
        }
      } else {
        // ---- PV on kst = V chunk s-4; wave owns 32-key slice ----
        const int vcb = (s - 4) * 256;
        v8h pfr[2];
#pragma unroll
        for (int qt = 0; qt < 2; ++qt)
          pfr[qt] =
              *(const v8h*)&s_lds[(qt * 16 + lm) * SP + vcb + w * 32 + lg * 8];
#pragma unroll
        for (int ft = 0; ft < 5; ++ft) {
          v8h bfr;
#pragma unroll
          for (int j = 0; j < 8; ++j)
            bfr[j] = kst[(w * 32 + lg * 8 + j) * KP + ft * 16 + lm];
          accO[0][ft] = __builtin_amdgcn_mfma_f32_16x16x32_f16(
              pfr[0], bfr, accO[0][ft], 0, 0, 0);
          accO[1][ft] = __builtin_amdgcn_mfma_f32_16x16x32_f16(
              pfr[1], bfr, accO[1][ft], 0, 0, 0);
        }
      }
      __syncthreads();  // all consumers of kst chunk s done
      if (s < 7) {
        lwrite();  // chunk s+1 -> kst
        int ns = s + 2;
        if (ns < 4) gload(kb, ns);
        else if (ns < 8) gload(vb, ns - 4);
        else if (h < 7)
          gload(qkv + (size_t)(b * 24 + 8 + h + 1) * NT * FP, 0);
        __syncthreads();  // chunk s+1 visible
      }
    }
    // ---- O epilogue: scale by inv, cross-wave reduce via s_lds (P dead) ----
    float* ored = (float*)s_lds;  // [8][16][84]
#pragma unroll
    for (int qt = 0; qt < 2; ++qt) {
#pragma unroll
      for (int ft = 0; ft < 5; ++ft)
#pragma unroll
        for (int r = 0; r < 4; ++r)
          ored[(w * 16 + lg * 4 + r) * 84 + ft * 16 + lm] =
              accO[qt][ft][r] * inv_lds[qt * 16 + lg * 4 + r];
      __syncthreads();
      for (int i = tid; i < 1280; i += 512) {
        int q = i / 80, f = i % 80;
        float ss = 0.f;
#pragma unroll
        for (int ww = 0; ww < 8; ++ww) ss += ored[(ww * 16 + q) * 84 + f];
        attn_out[((size_t)(b * 16 + h) * NT + t0 + qt * 16 + q) * NF + f] = ss;
      }
      __syncthreads();
    }
  }
  // ---- aw head-average write ----
#pragma unroll
  for (int rr = 0; rr < 2; ++rr) {
    float* ab = aw_avg + ((size_t)b * NT + t0 + grp + rr * 16) * NT;
#pragma unroll
    for (int k = 0; k < 16; ++k) {
      float2 v2;
      v2.x = avg[rr][2 * k] * 0.125f;
      v2.y = avg[rr][2 * k + 1] * 0.125f;
      *(float2*)&ab[lane * 2 + k * 64] = v2;
    }
  }
}

// ---------------------------------------------------------------------------
// Freq attention (scalar, fp16 inputs; unchanged).
// ---------------------------------------------------------------------------
__global__ __launch_bounds__(256) void freq_attn_k(
    const _Float16* __restrict__ qkv, float* __restrict__ attn_out) {
  __shared__ float a_lds[64][FP];
  __shared__ float b_lds[64][FP];
  __shared__ float c_lds[80][81];
  const int bh = blockIdx.x;
  const int b = bh >> 3, h = bh & 7;
  const _Float16* qb = qkv + (size_t)(b * 24 + h) * NT * FP;
  const _Float16* kb = qkv + (size_t)(b * 24 + 8 + h) * NT * FP;
  const _Float16* vb = qkv + (size_t)(b * 24 + 16 + h) * NT * FP;
  const int tid = threadIdx.x;
  const int f0 = (tid & 15) * 5, g0 = (tid >> 4) * 5;
  float acc[5][5];
#pragma unroll
  for (int i = 0; i < 5; ++i)
#pragma unroll
    for (int j = 0; j < 5; ++j) acc[i][j] = 0.f;

  for (int tt = 0; tt < 16; ++tt) {
    int t0 = tt * 64;
    for (int i = tid; i < 64 * 12; i += 256) {
      int r = i / 12, c = i % 12;
      v8h va = *(const v8h*)(qb + (size_t)(t0 + r) * FP + c * 8);
      v8h vb2 = *(const v8h*)(kb + (size_t)(t0 + r) * FP + c * 8);
#pragma unroll
      for (int j = 0; j < 8; ++j) {
        a_lds[r][c * 8 + j] = (float)va[j];
        b_lds[r][c * 8 + j] = (float)vb2[j];
      }
    }
    __syncthreads();
    for (int r = 0; r < 64; ++r) {
      float qv[5], kv[5];
#pragma unroll
      for (int i = 0; i < 5; ++i) {
        qv[i] = a_lds[r][f0 + i];
        kv[i] = b_lds[r][g0 + i];
      }
#pragma unroll
      for (int i = 0; i < 5; ++i)
#pragma unroll
        for (int j = 0; j < 5; ++j) acc[i][j] += qv[i] * kv[j];
    }
    __syncthreads();
  }
#pragma unroll
  for (int i = 0; i < 5; ++i)
#pragma unroll
    for (int j = 0; j < 5; ++j) c_lds[f0 + i][g0 + j] = acc[i][j];
  __syncthreads();
  if (tid < 80) {
    float m = -1e30f;
    for (int g = 0; g < 80; ++g) m = fmaxf(m, c_lds[tid][g]);
    float dsum = 0.f;
    for (int g = 0; g < 80; ++g) {
      float e = __expf(c_lds[tid][g] - m);
      dsum += e;
      c_lds[tid][g] = e;
    }
    float invd = 1.f / dsum;
    for (int g = 0; g < 80; ++g) c_lds[tid][g] *= invd;
  }
  __syncthreads();
  float* ob = attn_out + (size_t)(b * 16 + 8 + h) * NT * NF;
  for (int vt = 0; vt < 16; ++vt) {
    int t0 = vt * 64;
    for (int i = tid; i < 64 * 12; i += 256) {
      int r = i / 12, c = i % 12;
      v8h vv = *(const v8h*)(vb + (size_t)(t0 + r) * FP + c * 8);
#pragma unroll
      for (int j = 0; j < 8; ++j) a_lds[r][c * 8 + j] = (float)vv[j];
    }
    __syncthreads();
    const int t = tid & 63;
    const int fg = tid >> 6;
    float oacc[20];
#pragma unroll
    for (int i = 0; i < 20; ++i) oacc[i] = 0.f;
    for (int g = 0; g < 80; ++g) {
      float vv = a_lds[t][g];
#pragma unroll
      for (int i = 0; i < 20; ++i) oacc[i] += vv * c_lds[fg * 20 + i][g];
    }
    float4* ob4 = (float4*)(ob + (size_t)(t0 + t) * NF + fg * 20);
#pragma unroll
    for (int m4 = 0; m4 < 5; ++m4)
      ob4[m4] = make_float4(oacc[4 * m4], oacc[4 * m4 + 1], oacc[4 * m4 + 2],
                            oacc[4 * m4 + 3]);
    __syncthreads();
  }
}

// BN + relu: read fp16 y, write final fp32 out
__global__ __launch_bounds__(256) void bn_apply_out_k(
    const _Float16* __restrict__ y, const float* __restrict__ stats,
    const float* __restrict__ go, const float* __restrict__ bo,
    float* __restrict__ out) {
  const size_t n8 = OUT_ELEMS / 8;
  const size_t stride = (size_t)gridDim.x * blockDim.x;
  for (size_t idx = (size_t)blockIdx.x * blockDim.x + threadIdx.x; idx < n8;
       idx += stride) {
    int c = (int)((idx / (NT * NF / 8)) % 16);
    float g = go[c], be = bo[c];
    float mean = stats[c * 2 + 0], invstd = stats[c * 2 + 1];
    v8h v = ((const v8h*)y)[idx];
    float4 o0, o1;
    o0.x = fmaxf(((float)v[0] - mean) * invstd * g + be, 0.f);
    o0.y = fmaxf(((float)v[1] - mean) * invstd * g + be, 0.f);
    o0.z = fmaxf(((float)v[2] - mean) * invstd * g + be, 0.f);
    o0.w = fmaxf(((float)v[3] - mean) * invstd * g + be, 0.f);
    o1.x = fmaxf(((float)v[4] - mean) * invstd * g + be, 0.f);
    o1.y = fmaxf(((float)v[5] - mean) * invstd * g + be, 0.f);
    o1.z = fmaxf(((float)v[6] - mean) * invstd * g + be, 0.f);
    o1.w = fmaxf(((float)v[7] - mean) * invstd * g + be, 0.f);
    ((float4*)out)[idx * 2] = o0;
    ((float4*)out)[idx * 2 + 1] = o1;
  }
}

// ---------------------------------------------------------------------------
extern "C" void kernel_launch(void* const* d_in, const int* in_sizes, int n_in,
                              void* d_out, int out_size, void* d_ws,
                              size_t ws_size, hipStream_t stream) {
  const float* x = (const float*)d_in[0];
  const float* w_in = (const float*)d_in[1];
  const float* b_in = (const float*)d_in[2];
  const float* w_out = (const float*)d_in[3];
  const float* b_out = (const float*)d_in[4];
  const float* gq = (const float*)d_in[5];
  const float* bq = (const float*)d_in[6];
  const float* gk = (const float*)d_in[7];
  const float* bk = (const float*)d_in[8];
  const float* gv = (const float*)d_in[9];
  const float* bv = (const float*)d_in[10];
  const float* go = (const float*)d_in[11];
  const float* bo = (const float*)d_in[12];

  float* out = (float*)d_out;                    // (16,16,1024,80) fp32
  float* aw = out + OUT_ELEMS;                   // (16,1024,1024) fp32
  char* wsb = (char*)d_ws;
  _Float16* qkvb = (_Float16*)wsb;               // [0, 75,497,472)
  _Float16* yh = (_Float16*)wsb;                 // fp16 y aliases dead qkvb
  _Float16* xcl = (_Float16*)(wsb + 75497472);   // 44,040,192 B
  _Float16* acl = xcl;                           // reuses xcl region
  float* partials = (float*)(wsb + 119537664);   // 768 floats
  float* stats1 = partials + 768;                // 48
  float* stats2 = stats1 + 48;                   // 32

  cl_k<<<dim3(64, 16), 256, 0, stream>>>(x, xcl);
  conv_mfma_k<2, FP, true, true>
      <<<dim3(64, 16), 512, 0, stream>>>(xcl, w_in, b_in, qkvb, 24);
  bn_stats_h_k<<<dim3(16, 24), 256, 0, stream>>>(qkvb, partials);
  bn_finalize_k<<<1, 64, 0, stream>>>(partials, stats1, 24);
  bn_apply_qkv_k<<<2048, 256, 0, stream>>>(qkvb, stats1, gq, bq, gk, bk, gv,
                                           bv);
  time_attn_k<<<dim3(32, 16), 512, 0, stream>>>(qkvb, out, aw);
  freq_attn_k<<<128, 256, 0, stream>>>(qkvb, out);
  cl_k<<<dim3(64, 16), 256, 0, stream>>>(out, acl);
  conv_mfma_k<1, NF, false, false>
      <<<dim3(64, 16), 512, 0, stream>>>(acl, w_out, b_out, yh, 16);
  bn_stats_y_k<<<dim3(16, 16), 256, 0, stream>>>(yh, partials);
  bn_finalize_k<<<1, 64, 0, stream>>>(partials, stats2, 16);
  bn_apply_out_k<<<2048, 256, 0, stream>>>(yh, stats2, go, bo, out);
}

// Round 7
// 472.599 us; speedup vs baseline: 12.7542x; 1.3799x over previous
//
#include <hip/hip_runtime.h>
#include <cstdint>
#include <cstddef>

// Problem constants: B=16, E=16, T=1024, F=80, H=8, 3H=24 qkv channels
#define NB 16
#define NT 1024
#define NF 80
#define NH 8
#define FP 96   // qkv f padded to 96 (3 x K=32 MFMA steps); pad is zero
#define FS 84   // channels-last padded f-sites (site s <-> f = s-1; 0,81..83 zero)
#define SP 1032 // time_attn S-strip row stride (fp16)
#define KP 108  // time_attn kst/q_lds row stride (fp16)

typedef _Float16 v8h __attribute__((ext_vector_type(8)));  // 8 fp16 (4 VGPRs)
typedef _Float16 v4h __attribute__((ext_vector_type(4)));  // 4 fp16 (8 B)
typedef _Float16 v2h __attribute__((ext_vector_type(2)));  // 2 fp16 (4 B)
typedef float v4f __attribute__((ext_vector_type(4)));     // mfma f32x4 acc

static const size_t OUT_ELEMS = (size_t)NB * 16 * NT * NF;  // 20,971,520

// ---------------------------------------------------------------------------
// channels-last transpose: fp32 NCHW (16 ch) -> fp16 [b][t][84][16]
// ---------------------------------------------------------------------------
__global__ __launch_bounds__(256) void cl_k(const float* __restrict__ src,
                                            _Float16* __restrict__ dst) {
  const int b = blockIdx.y, t0 = blockIdx.x * 16;
  for (int i = threadIdx.x; i < 16 * FS; i += 256) {
    int lt = i / FS, s = i % FS;
    int t = t0 + lt, f = s - 1;
    v8h lo = (v8h)(_Float16)0.f, hi = (v8h)(_Float16)0.f;
    if (f >= 0 && f < NF) {
#pragma unroll
      for (int c = 0; c < 8; ++c)
        lo[c] = (_Float16)src[((size_t)(b * 16 + c) * NT + t) * NF + f];
#pragma unroll
      for (int c = 0; c < 8; ++c)
        hi[c] = (_Float16)src[((size_t)(b * 16 + 8 + c) * NT + t) * NF + f];
    }
    _Float16* d = dst + ((size_t)(b * NT + t) * FS + s) * 16;
    *(v8h*)d = lo;
    *(v8h*)(d + 8) = hi;
  }
}

// ---------------------------------------------------------------------------
// conv3x3 SAME as MFMA implicit GEMM over channels-last fp16 input.
// ---------------------------------------------------------------------------
template <int OCT, int OSTRIDE, bool QSCALE, bool PADOUT>
__global__ __launch_bounds__(512) void conv_mfma_k(
    const _Float16* __restrict__ xcl, const float* __restrict__ w,
    const float* __restrict__ bias, _Float16* __restrict__ out, int CO) {
  __shared__ _Float16 axt[18][FS * 16];            // 48.4 KB
  __shared__ _Float16 wlds[3][2][OCT * 16][32];
  __shared__ float blds[32];
  const int b = blockIdx.y, t0 = blockIdx.x * 16;
  const int tid = threadIdx.x;
  const int NW = 3 * 2 * OCT * 16 * 32;
  for (int i = tid; i < NW; i += 512) {
    int kk = i % 32;
    int oc = (i / 32) % (OCT * 16);
    int ck = (i / (32 * OCT * 16)) % 2;
    int kt = i / (64 * OCT * 16);
    int kg = ck * 32 + kk;
    float v = 0.f;
    if (oc < CO && kg < 48) {
      int c = kg & 15, kf = kg >> 4;
      v = w[((oc * 16 + c) * 3 + kt) * 3 + kf];
      if (QSCALE && oc < 8) v *= 0.25f;
    }
    wlds[kt][ck][oc][kk] = (_Float16)v;
  }
  if (tid < 32) {
    float v = (tid < CO) ? bias[tid] : 0.f;
    if (QSCALE && tid < 8) v *= 0.25f;
    blds[tid] = v;
  }
  for (int i = tid; i < 18 * 168; i += 512) {
    int r = i / 168, j = i % 168;
    int t = t0 + r - 1;
    int4 v = {0, 0, 0, 0};
    if (t >= 0 && t < NT)
      v = ((const int4*)(xcl + (size_t)(b * NT + t) * FS * 16))[j];
    ((int4*)axt[r])[j] = v;
  }
  __syncthreads();
  const int wv = tid >> 6, l = tid & 63, lg = l >> 4, lm = l & 15;
  v8h bfr[3][2][OCT];
#pragma unroll
  for (int kt = 0; kt < 3; ++kt)
#pragma unroll
    for (int ck = 0; ck < 2; ++ck)
#pragma unroll
      for (int ot = 0; ot < OCT; ++ot)
        bfr[kt][ck][ot] = *(const v8h*)&wlds[kt][ck][ot * 16 + lm][lg * 8];
#pragma unroll
  for (int li = 0; li < 2; ++li) {
    const int lt = wv * 2 + li;
    const int tt = t0 + lt;
#pragma unroll
    for (int f0 = 0; f0 < 80; f0 += 16) {
      v4f acc[OCT];
#pragma unroll
      for (int ot = 0; ot < OCT; ++ot) acc[ot] = (v4f){0.f, 0.f, 0.f, 0.f};
#pragma unroll
      for (int kt = 0; kt < 3; ++kt)
#pragma unroll
        for (int ck = 0; ck < 2; ++ck) {
          v8h afr =
              *(const v8h*)&axt[lt + kt][(f0 + lm) * 16 + ck * 32 + lg * 8];
#pragma unroll
          for (int ot = 0; ot < OCT; ++ot)
            acc[ot] = __builtin_amdgcn_mfma_f32_16x16x32_f16(
                afr, bfr[kt][ck][ot], acc[ot], 0, 0, 0);
        }
#pragma unroll
      for (int ot = 0; ot < OCT; ++ot) {
        int oc = ot * 16 + lm;
        if (oc < CO) {
          float bv = blds[oc];
          v4h o;
#pragma unroll
          for (int r = 0; r < 4; ++r) o[r] = (_Float16)(acc[ot][r] + bv);
          *(v4h*)(out + ((size_t)(b * CO + oc) * NT + tt) * OSTRIDE + f0 +
                  lg * 4) = o;
        }
      }
    }
  }
  if constexpr (PADOUT) {
    for (int i = tid; i < CO * 16 * 2; i += 512) {
      int oc = i / 32, lt2 = (i / 2) % 16, half = i & 1;
      int4 z = {0, 0, 0, 0};
      ((int4*)(out + ((size_t)(b * CO + oc) * NT + t0 + lt2) * OSTRIDE +
               80))[half] = z;
    }
  }
}

// ---------------------------------------------------------------------------
// BN stats over fp16 qkv [b][24][t][96]
// ---------------------------------------------------------------------------
__global__ __launch_bounds__(256) void bn_stats_h_k(
    const _Float16* __restrict__ x, float* __restrict__ partials) {
  const int b = blockIdx.x, c = blockIdx.y;
  const v8h* p = (const v8h*)(x + (size_t)(b * 24 + c) * NT * FP);
  float s = 0.f, s2 = 0.f;
  for (int i = threadIdx.x; i < NT * FP / 8; i += 256) {
    v8h v = p[i];
#pragma unroll
    for (int j = 0; j < 8; ++j) {
      float f = (float)v[j];
      s += f;
      s2 += f * f;
    }
  }
  __shared__ float rs[256], rs2[256];
  rs[threadIdx.x] = s;
  rs2[threadIdx.x] = s2;
  __syncthreads();
  for (int off = 128; off > 0; off >>= 1) {
    if ((int)threadIdx.x < off) {
      rs[threadIdx.x] += rs[threadIdx.x + off];
      rs2[threadIdx.x] += rs2[threadIdx.x + off];
    }
    __syncthreads();
  }
  if (threadIdx.x == 0) {
    partials[(c * 16 + b) * 2 + 0] = rs[0];
    partials[(c * 16 + b) * 2 + 1] = rs2[0];
  }
}

// BN stats over fp16 y [b][16][t][80]
__global__ __launch_bounds__(256) void bn_stats_y_k(
    const _Float16* __restrict__ x, float* __restrict__ partials) {
  const int b = blockIdx.x, c = blockIdx.y;
  const v8h* p = (const v8h*)(x + (size_t)(b * 16 + c) * (NT * NF));
  float s = 0.f, s2 = 0.f;
  for (int i = threadIdx.x; i < NT * NF / 8; i += 256) {
    v8h v = p[i];
#pragma unroll
    for (int j = 0; j < 8; ++j) {
      float f = (float)v[j];
      s += f;
      s2 += f * f;
    }
  }
  __shared__ float rs[256], rs2[256];
  rs[threadIdx.x] = s;
  rs2[threadIdx.x] = s2;
  __syncthreads();
  for (int off = 128; off > 0; off >>= 1) {
    if ((int)threadIdx.x < off) {
      rs[threadIdx.x] += rs[threadIdx.x + off];
      rs2[threadIdx.x] += rs2[threadIdx.x + off];
    }
    __syncthreads();
  }
  if (threadIdx.x == 0) {
    partials[(c * 16 + b) * 2 + 0] = rs[0];
    partials[(c * 16 + b) * 2 + 1] = rs2[0];
  }
}

__global__ void bn_finalize_k(const float* __restrict__ partials,
                              float* __restrict__ stats, int C) {
  int c = threadIdx.x;
  if (c < C) {
    float s = 0.f, s2 = 0.f;
    for (int i = 0; i < 16; ++i) {
      s += partials[(c * 16 + i) * 2 + 0];
      s2 += partials[(c * 16 + i) * 2 + 1];
    }
    const float N = 16.0f * (float)(NT * NF);
    float mean = s / N;
    float var = s2 / N - mean * mean;
    stats[c * 2 + 0] = mean;
    stats[c * 2 + 1] = rsqrtf(var + 1e-5f);
  }
}

// BN affine + relu in place on fp16 qkv
__global__ __launch_bounds__(256) void bn_apply_qkv_k(
    _Float16* __restrict__ qkv, const float* __restrict__ stats,
    const float* __restrict__ gq, const float* __restrict__ bq,
    const float* __restrict__ gk, const float* __restrict__ bk,
    const float* __restrict__ gv, const float* __restrict__ bv) {
  const size_t n8 = (size_t)NB * 24 * NT * 12;
  const size_t stride = (size_t)gridDim.x * blockDim.x;
  for (size_t idx = (size_t)blockIdx.x * blockDim.x + threadIdx.x; idx < n8;
       idx += stride) {
    int fc = (int)(idx % 12);
    if (fc >= 10) continue;  // f 80..95 stays zero
    int c = (int)((idx / (NT * 12)) % 24);
    float g, be;
    if (c < 8) { g = gq[c]; be = bq[c]; }
    else if (c < 16) { g = gk[c - 8]; be = bk[c - 8]; }
    else { g = gv[c - 16]; be = bv[c - 16]; }
    float mean = stats[c * 2 + 0], invstd = stats[c * 2 + 1];
    v8h v = ((v8h*)qkv)[idx];
#pragma unroll
    for (int j = 0; j < 8; ++j) {
      float f = (float)v[j];
      f = fmaxf((f - mean) * invstd * g + be, 0.f);
      v[j] = (_Float16)f;
    }
    ((v8h*)qkv)[idx] = v;
  }
}

// ---------------------------------------------------------------------------
// Time attention, MFMA fp16 (unchanged from round 6).
// ---------------------------------------------------------------------------
__global__ __launch_bounds__(512) void time_attn_k(
    const _Float16* __restrict__ qkv, float* __restrict__ attn_out,
    float* __restrict__ aw_avg) {
  __shared__ _Float16 s_lds[32 * SP];   // 66 KB; reused as ored fp32
  __shared__ _Float16 q_lds[32 * KP];   // 6.9 KB
  __shared__ _Float16 kst[256 * KP];    // 55.3 KB
  __shared__ float inv_lds[32];
  const int b = blockIdx.y, t0 = blockIdx.x * 32;
  const int tid = threadIdx.x;
  const int w = tid >> 6, l = tid & 63, lg = l >> 4, lm = l & 15;
  const int grp = tid >> 5, lane = tid & 31;
  float avg[2][32];
#pragma unroll
  for (int rr = 0; rr < 2; ++rr)
#pragma unroll
    for (int k = 0; k < 32; ++k) avg[rr][k] = 0.f;

  int4 rb[6];
  auto gload = [&](const _Float16* base, int chunk) {
    const int4* src = (const int4*)(base + (size_t)chunk * 256 * FP);
#pragma unroll
    for (int u = 0; u < 6; ++u) rb[u] = src[tid + u * 512];
  };
  auto lwrite = [&]() {
#pragma unroll
    for (int u = 0; u < 6; ++u) {
      int i = tid + u * 512, row = i / 12, j = i % 12;
      int2* d = (int2*)&kst[row * KP + j * 8];
      d[0] = make_int2(rb[u].x, rb[u].y);
      d[1] = make_int2(rb[u].z, rb[u].w);
    }
  };

  gload(qkv + (size_t)(b * 24 + 8) * NT * FP, 0);

  for (int h = 0; h < NH; ++h) {
    const _Float16* qb = qkv + ((size_t)(b * 24 + h) * NT + t0) * FP;
    const _Float16* kb = qkv + (size_t)(b * 24 + 8 + h) * NT * FP;
    const _Float16* vb = qkv + (size_t)(b * 24 + 16 + h) * NT * FP;
    int4 qreg = {0, 0, 0, 0};
    if (tid < 384) qreg = ((const int4*)qb)[tid];
    lwrite();  // K0 -> kst
    if (tid < 384) {
      int row = tid / 12, j = tid % 12;
      int2* d = (int2*)&q_lds[row * KP + j * 8];
      d[0] = make_int2(qreg.x, qreg.y);
      d[1] = make_int2(qreg.z, qreg.w);
    }
    gload(kb, 1);
    __syncthreads();
    v8h afr[2][3];
#pragma unroll
    for (int qt = 0; qt < 2; ++qt)
#pragma unroll
      for (int kk = 0; kk < 3; ++kk) {
        v4h a0 = *(const v4h*)&q_lds[(qt * 16 + lm) * KP + kk * 32 + lg * 8];
        v4h a1 =
            *(const v4h*)&q_lds[(qt * 16 + lm) * KP + kk * 32 + lg * 8 + 4];
        afr[qt][kk] = __builtin_shufflevector(a0, a1, 0, 1, 2, 3, 4, 5, 6, 7);
      }
    v4f accO[2][5];
#pragma unroll
    for (int qt = 0; qt < 2; ++qt)
#pragma unroll
      for (int ft = 0; ft < 5; ++ft) accO[qt][ft] = (v4f){0.f, 0.f, 0.f, 0.f};

    for (int s = 0; s < 8; ++s) {
      if (s == 4) {
#pragma unroll
        for (int rr = 0; rr < 2; ++rr) {
          const int row = grp + rr * 16;
          _Float16* srow = &s_lds[row * SP];
          float m = -1e30f;
#pragma unroll
          for (int k = 0; k < 16; ++k) {
            v2h e2 = *(const v2h*)&srow[lane * 2 + k * 64];
            m = fmaxf(m, fmaxf((float)e2[0], (float)e2[1]));
          }
#pragma unroll
          for (int mk = 16; mk; mk >>= 1) m = fmaxf(m, __shfl_xor(m, mk, 32));
          float d = 0.f;
#pragma unroll
          for (int k = 0; k < 16; ++k) {
            v2h e2 = *(const v2h*)&srow[lane * 2 + k * 64];
            float e0 = __expf((float)e2[0] - m);
            float e1 = __expf((float)e2[1] - m);
            d += e0 + e1;
            v2h w2;
            w2[0] = (_Float16)e0;
            w2[1] = (_Float16)e1;
            *(v2h*)&srow[lane * 2 + k * 64] = w2;
          }
#pragma unroll
          for (int mk = 16; mk; mk >>= 1) d += __shfl_xor(d, mk, 32);
          float inv = 1.f / d;
          if (lane == 0) inv_lds[row] = inv;
#pragma unroll
          for (int k = 0; k < 16; ++k) {
            v2h e2 = *(const v2h*)&srow[lane * 2 + k * 64];
            avg[rr][2 * k] += (float)e2[0] * inv;
            avg[rr][2 * k + 1] += (float)e2[1] * inv;
          }
        }
        __syncthreads();
      }
      if (s < 4) {
#pragma unroll
        for (int tt = 0; tt < 2; ++tt) {
          const int rowb = (w * 2 + tt) * 16;
          const int rbase = (rowb + lm) * KP;
          v8h bfr[3];
#pragma unroll
          for (int kk = 0; kk < 3; ++kk) {
            v4h b0 = *(const v4h*)&kst[rbase + kk * 32 + lg * 8];
            v4h b1 = *(const v4h*)&kst[rbase + kk * 32 + lg * 8 + 4];
            bfr[kk] = __builtin_shufflevector(b0, b1, 0, 1, 2, 3, 4, 5, 6, 7);
          }
          const int sc = s * 256 + rowb + lm;
#pragma unroll
          for (int qt = 0; qt < 2; ++qt) {
            v4f acc = (v4f){0.f, 0.f, 0.f, 0.f};
#pragma unroll
            for (int kk = 0; kk < 3; ++kk)
              acc = __builtin_amdgcn_mfma_f32_16x16x32_f16(afr[qt][kk],
                                                           bfr[kk], acc, 0, 0,
                                                           0);
#pragma unroll
            for (int r = 0; r < 4; ++r)
              s_lds[(qt * 16 + lg * 4 + r) * SP + sc] = (_Float16)acc[r];
          }
        }
      } else {
        const int vcb = (s - 4) * 256;
        v8h pfr[2];
#pragma unroll
        for (int qt = 0; qt < 2; ++qt)
          pfr[qt] =
              *(const v8h*)&s_lds[(qt * 16 + lm) * SP + vcb + w * 32 + lg * 8];
#pragma unroll
        for (int ft = 0; ft < 5; ++ft) {
          v8h bfr;
#pragma unroll
          for (int j = 0; j < 8; ++j)
            bfr[j] = kst[(w * 32 + lg * 8 + j) * KP + ft * 16 + lm];
          accO[0][ft] = __builtin_amdgcn_mfma_f32_16x16x32_f16(
              pfr[0], bfr, accO[0][ft], 0, 0, 0);
          accO[1][ft] = __builtin_amdgcn_mfma_f32_16x16x32_f16(
              pfr[1], bfr, accO[1][ft], 0, 0, 0);
        }
      }
      __syncthreads();
      if (s < 7) {
        lwrite();
        int ns = s + 2;
        if (ns < 4) gload(kb, ns);
        else if (ns < 8) gload(vb, ns - 4);
        else if (h < 7)
          gload(qkv + (size_t)(b * 24 + 8 + h + 1) * NT * FP, 0);
        __syncthreads();
      }
    }
    float* ored = (float*)s_lds;  // [8][16][84]
#pragma unroll
    for (int qt = 0; qt < 2; ++qt) {
#pragma unroll
      for (int ft = 0; ft < 5; ++ft)
#pragma unroll
        for (int r = 0; r < 4; ++r)
          ored[(w * 16 + lg * 4 + r) * 84 + ft * 16 + lm] =
              accO[qt][ft][r] * inv_lds[qt * 16 + lg * 4 + r];
      __syncthreads();
      for (int i = tid; i < 1280; i += 512) {
        int q = i / 80, f = i % 80;
        float ss = 0.f;
#pragma unroll
        for (int ww = 0; ww < 8; ++ww) ss += ored[(ww * 16 + q) * 84 + f];
        attn_out[((size_t)(b * 16 + h) * NT + t0 + qt * 16 + q) * NF + f] = ss;
      }
      __syncthreads();
    }
  }
#pragma unroll
  for (int rr = 0; rr < 2; ++rr) {
    float* ab = aw_avg + ((size_t)b * NT + t0 + grp + rr * 16) * NT;
#pragma unroll
    for (int k = 0; k < 16; ++k) {
      float2 v2;
      v2.x = avg[rr][2 * k] * 0.125f;
      v2.y = avg[rr][2 * k + 1] * 0.125f;
      *(float2*)&ab[lane * 2 + k * 64] = v2;
    }
  }
}

// ---------------------------------------------------------------------------
// Freq attention stage 1: partial C[f,g] = sum_t q[t,f] k[t,g] over a 128-t
// slice. Grid (8 tc, 128 bh), 1 wave. A/B fragments gathered (2-way-free
// banks at stride 100). C written fp32 to Cp[bh][tc][80][80].
// ---------------------------------------------------------------------------
__global__ __launch_bounds__(64) void freq_qk_k(
    const _Float16* __restrict__ qkv, float* __restrict__ Cp) {
  __shared__ _Float16 qs[128 * 100];  // 25.6 KB
  __shared__ _Float16 ks[128 * 100];  // 25.6 KB
  const int tc = blockIdx.x, bh = blockIdx.y;
  const int b = bh >> 3, h = bh & 7;
  const int t0 = tc * 128;
  const _Float16* qb = qkv + ((size_t)(b * 24 + h) * NT + t0) * FP;
  const _Float16* kb = qkv + ((size_t)(b * 24 + 8 + h) * NT + t0) * FP;
  const int tid = threadIdx.x;
  for (int i = tid; i < 1536; i += 64) {
    int row = i / 12, c = i % 12;
    int4 vq = ((const int4*)qb)[i];
    int4 vk = ((const int4*)kb)[i];
    int2* dq = (int2*)&qs[row * 100 + c * 8];
    dq[0] = make_int2(vq.x, vq.y);
    dq[1] = make_int2(vq.z, vq.w);
    int2* dk = (int2*)&ks[row * 100 + c * 8];
    dk[0] = make_int2(vk.x, vk.y);
    dk[1] = make_int2(vk.z, vk.w);
  }
  __syncthreads();
  const int lg = tid >> 4, lm = tid & 15;
  v4f acc[5][5];
#pragma unroll
  for (int fr = 0; fr < 5; ++fr)
#pragma unroll
    for (int gc = 0; gc < 5; ++gc) acc[fr][gc] = (v4f){0.f, 0.f, 0.f, 0.f};
#pragma unroll
  for (int kk = 0; kk < 4; ++kk) {
    v8h afr[5];
#pragma unroll
    for (int fr = 0; fr < 5; ++fr)
#pragma unroll
      for (int j = 0; j < 8; ++j)
        afr[fr][j] = qs[(kk * 32 + lg * 8 + j) * 100 + fr * 16 + lm];
#pragma unroll
    for (int gc = 0; gc < 5; ++gc) {
      v8h bfr;
#pragma unroll
      for (int j = 0; j < 8; ++j)
        bfr[j] = ks[(kk * 32 + lg * 8 + j) * 100 + gc * 16 + lm];
#pragma unroll
      for (int fr = 0; fr < 5; ++fr)
        acc[fr][gc] = __builtin_amdgcn_mfma_f32_16x16x32_f16(afr[fr], bfr,
                                                             acc[fr][gc], 0,
                                                             0, 0);
    }
  }
  float* cpb = Cp + ((size_t)bh * 8 + tc) * 6400;
#pragma unroll
  for (int fr = 0; fr < 5; ++fr)
#pragma unroll
    for (int gc = 0; gc < 5; ++gc)
#pragma unroll
      for (int r = 0; r < 4; ++r)
        cpb[(fr * 16 + lg * 4 + r) * 80 + gc * 16 + lm] = acc[fr][gc][r];
}

// ---------------------------------------------------------------------------
// Freq attention stage 2: sum 8 partials, row softmax, P fp16 [80][96]
// (g 80..95 zero). Grid 128 (bh), 128 threads (f = tid < 80 active).
// ---------------------------------------------------------------------------
__global__ __launch_bounds__(128) void freq_sm_k(const float* __restrict__ Cp,
                                                 _Float16* __restrict__ P) {
  const int bh = blockIdx.x;
  const int f = threadIdx.x;
  if (f >= 80) return;
  float c[80];
#pragma unroll
  for (int g = 0; g < 80; ++g) c[g] = 0.f;
  const float* base = Cp + (size_t)bh * 8 * 6400 + f * 80;
#pragma unroll
  for (int tc = 0; tc < 8; ++tc) {
    const float4* p4 = (const float4*)(base + tc * 6400);
#pragma unroll
    for (int g4 = 0; g4 < 20; ++g4) {
      float4 v = p4[g4];
      c[g4 * 4 + 0] += v.x;
      c[g4 * 4 + 1] += v.y;
      c[g4 * 4 + 2] += v.z;
      c[g4 * 4 + 3] += v.w;
    }
  }
  float m = -1e30f;
#pragma unroll
  for (int g = 0; g < 80; ++g) m = fmaxf(m, c[g]);
  float d = 0.f;
#pragma unroll
  for (int g = 0; g < 80; ++g) {
    float e = __expf(c[g] - m);
    d += e;
    c[g] = e;
  }
  float inv = 1.f / d;
  _Float16* pb = P + (size_t)bh * 80 * 96 + (size_t)f * 96;
#pragma unroll
  for (int c8 = 0; c8 < 10; ++c8) {
    v8h v;
#pragma unroll
    for (int j = 0; j < 8; ++j) v[j] = (_Float16)(c[c8 * 8 + j] * inv);
    *(v8h*)(pb + c8 * 8) = v;
  }
  v8h z = (v8h)(_Float16)0.f;
  *(v8h*)(pb + 80) = z;
  *(v8h*)(pb + 88) = z;
}

// ---------------------------------------------------------------------------
// Freq attention stage 3: out[t,f] = sum_g v[t,g] P[f,g] -> channels 8..15.
// Grid (8 tc, 128 bh), 256 threads (4 waves). All fragments contiguous.
// ---------------------------------------------------------------------------
__global__ __launch_bounds__(256) void freq_pv_k(
    const _Float16* __restrict__ qkv, const _Float16* __restrict__ P,
    float* __restrict__ attn_out) {
  __shared__ _Float16 vs[128 * 104];  // 26.6 KB
  __shared__ _Float16 ps[80 * 104];   // 16.6 KB
  const int tc = blockIdx.x, bh = blockIdx.y;
  const int b = bh >> 3, h = bh & 7;
  const int t0 = tc * 128;
  const _Float16* vb = qkv + ((size_t)(b * 24 + 16 + h) * NT + t0) * FP;
  const _Float16* pb = P + (size_t)bh * 80 * 96;
  const int tid = threadIdx.x;
  for (int i = tid; i < 1536; i += 256) {
    int row = i / 12, c = i % 12;
    *(int4*)&vs[row * 104 + c * 8] = ((const int4*)vb)[i];
  }
  for (int i = tid; i < 960; i += 256) {
    int row = i / 12, c = i % 12;
    *(int4*)&ps[row * 104 + c * 8] = ((const int4*)pb)[i];
  }
  __syncthreads();
  const int w = tid >> 6, l = tid & 63, lg = l >> 4, lm = l & 15;
  v8h bfr[5][3];
#pragma unroll
  for (int fc = 0; fc < 5; ++fc)
#pragma unroll
    for (int kk = 0; kk < 3; ++kk)
      bfr[fc][kk] = *(const v8h*)&ps[(fc * 16 + lm) * 104 + kk * 32 + lg * 8];
#pragma unroll
  for (int tt2 = 0; tt2 < 2; ++tt2) {
    const int tt = w + tt2 * 4;
    v8h afr[3];
#pragma unroll
    for (int kk = 0; kk < 3; ++kk)
      afr[kk] = *(const v8h*)&vs[(tt * 16 + lm) * 104 + kk * 32 + lg * 8];
    float* ob =
        attn_out + ((size_t)(b * 16 + 8 + h) * NT + t0 + tt * 16) * NF;
#pragma unroll
    for (int fc = 0; fc < 5; ++fc) {
      v4f acc = (v4f){0.f, 0.f, 0.f, 0.f};
#pragma unroll
      for (int kk = 0; kk < 3; ++kk)
        acc = __builtin_amdgcn_mfma_f32_16x16x32_f16(afr[kk], bfr[fc][kk],
                                                     acc, 0, 0, 0);
#pragma unroll
      for (int r = 0; r < 4; ++r)
        ob[(lg * 4 + r) * NF + fc * 16 + lm] = acc[r];
    }
  }
}

// BN + relu: read fp16 y, write final fp32 out
__global__ __launch_bounds__(256) void bn_apply_out_k(
    const _Float16* __restrict__ y, const float* __restrict__ stats,
    const float* __restrict__ go, const float* __restrict__ bo,
    float* __restrict__ out) {
  const size_t n8 = OUT_ELEMS / 8;
  const size_t stride = (size_t)gridDim.x * blockDim.x;
  for (size_t idx = (size_t)blockIdx.x * blockDim.x + threadIdx.x; idx < n8;
       idx += stride) {
    int c = (int)((idx / (NT * NF / 8)) % 16);
    float g = go[c], be = bo[c];
    float mean = stats[c * 2 + 0], invstd = stats[c * 2 + 1];
    v8h v = ((const v8h*)y)[idx];
    float4 o0, o1;
    o0.x = fmaxf(((float)v[0] - mean) * invstd * g + be, 0.f);
    o0.y = fmaxf(((float)v[1] - mean) * invstd * g + be, 0.f);
    o0.z = fmaxf(((float)v[2] - mean) * invstd * g + be, 0.f);
    o0.w = fmaxf(((float)v[3] - mean) * invstd * g + be, 0.f);
    o1.x = fmaxf(((float)v[4] - mean) * invstd * g + be, 0.f);
    o1.y = fmaxf(((float)v[5] - mean) * invstd * g + be, 0.f);
    o1.z = fmaxf(((float)v[6] - mean) * invstd * g + be, 0.f);
    o1.w = fmaxf(((float)v[7] - mean) * invstd * g + be, 0.f);
    ((float4*)out)[idx * 2] = o0;
    ((float4*)out)[idx * 2 + 1] = o1;
  }
}

// ---------------------------------------------------------------------------
extern "C" void kernel_launch(void* const* d_in, const int* in_sizes, int n_in,
                              void* d_out, int out_size, void* d_ws,
                              size_t ws_size, hipStream_t stream) {
  const float* x = (const float*)d_in[0];
  const float* w_in = (const float*)d_in[1];
  const float* b_in = (const float*)d_in[2];
  const float* w_out = (const float*)d_in[3];
  const float* b_out = (const float*)d_in[4];
  const float* gq = (const float*)d_in[5];
  const float* bq = (const float*)d_in[6];
  const float* gk = (const float*)d_in[7];
  const float* bk = (const float*)d_in[8];
  const float* gv = (const float*)d_in[9];
  const float* bv = (const float*)d_in[10];
  const float* go = (const float*)d_in[11];
  const float* bo = (const float*)d_in[12];

  float* out = (float*)d_out;                    // (16,16,1024,80) fp32
  float* aw = out + OUT_ELEMS;                   // (16,1024,1024) fp32
  char* wsb = (char*)d_ws;
  _Float16* qkvb = (_Float16*)wsb;               // [0, 75,497,472)
  _Float16* yh = (_Float16*)wsb;                 // fp16 y aliases dead qkvb
  _Float16* xcl = (_Float16*)(wsb + 75497472);   // 44,040,192 B scratch region
  _Float16* acl = xcl;                           // conv_out staging (later)
  float* Cp = (float*)(wsb + 75497472);          // 26,214,400 B (freq partials)
  _Float16* Pf = (_Float16*)(wsb + 101711872);   // 1,966,080 B (freq probs)
  float* partials = (float*)(wsb + 119537664);   // 768 floats
  float* stats1 = partials + 768;                // 48
  float* stats2 = stats1 + 48;                   // 32

  cl_k<<<dim3(64, 16), 256, 0, stream>>>(x, xcl);
  conv_mfma_k<2, FP, true, true>
      <<<dim3(64, 16), 512, 0, stream>>>(xcl, w_in, b_in, qkvb, 24);
  bn_stats_h_k<<<dim3(16, 24), 256, 0, stream>>>(qkvb, partials);
  bn_finalize_k<<<1, 64, 0, stream>>>(partials, stats1, 24);
  bn_apply_qkv_k<<<2048, 256, 0, stream>>>(qkvb, stats1, gq, bq, gk, bk, gv,
                                           bv);
  time_attn_k<<<dim3(32, 16), 512, 0, stream>>>(qkvb, out, aw);
  freq_qk_k<<<dim3(8, 128), 64, 0, stream>>>(qkvb, Cp);
  freq_sm_k<<<128, 128, 0, stream>>>(Cp, Pf);
  freq_pv_k<<<dim3(8, 128), 256, 0, stream>>>(qkvb, Pf, out);
  cl_k<<<dim3(64, 16), 256, 0, stream>>>(out, acl);
  conv_mfma_k<1, NF, false, false>
      <<<dim3(64, 16), 512, 0, stream>>>(acl, w_out, b_out, yh, 16);
  bn_stats_y_k<<<dim3(16, 16), 256, 0, stream>>>(yh, partials);
  bn_finalize_k<<<1, 64, 0, stream>>>(partials, stats2, 16);
  bn_apply_out_k<<<2048, 256, 0, stream>>>(yh, stats2, go, bo, out);
}